// Round 1
// baseline (2235.238 us; speedup 1.0000x reference)
//
#include <hip/hip_runtime.h>

#define W 128

__device__ __forceinline__ float lrelu(float x) { return x > 0.f ? x : 0.01f * x; }

// Monotonic uint32 encoding of float for atomicMax-based segment max.
// enc(f) >= 0x00800000 for any finite f, so 0 is a safe "empty" sentinel.
__device__ __forceinline__ unsigned enc_f(float f) {
    unsigned b = __float_as_uint(f);
    return (b & 0x80000000u) ? ~b : (b | 0x80000000u);
}
__device__ __forceinline__ float dec_f(unsigned e) {
    unsigned b = (e & 0x80000000u) ? (e ^ 0x80000000u) : ~e;
    return __uint_as_float(b);
}

// ---- initial embed: out[row,c] = lrelu(b[c] + sum_k in[row,k]*Wt[k,c]) ----
template <int K>
__global__ void embed_kernel(const float* __restrict__ in, const float* __restrict__ Wt,
                             const float* __restrict__ bias, float* __restrict__ out, int n) {
    int t = blockIdx.x * 256 + threadIdx.x;
    int row = t >> 7, c = t & 127;
    if (row >= n) return;
    float s = bias[c];
#pragma unroll
    for (int k = 0; k < K; k++) s += in[row * K + k] * Wt[k * W + c];
    out[row * W + c] = lrelu(s);
}

// ---- V2E scatter: x_v recomputed on the fly (K=3) ----
__global__ void scatter_v2e(const float* __restrict__ verts, const float* __restrict__ Wv,
                            const float* __restrict__ bv, const float* __restrict__ x_e,
                            const int* __restrict__ iv, const int* __restrict__ ie,
                            unsigned* __restrict__ maxbuf, int npairs) {
    int t = blockIdx.x * 256 + threadIdx.x;
    int i = t >> 7, c = t & 127;
    if (i >= npairs) return;
    int v = iv[i], e = ie[i];
    float s = bv[c];
#pragma unroll
    for (int k = 0; k < 3; k++) s += verts[v * 3 + k] * Wv[k * W + c];
    float d = x_e[e * W + c] - lrelu(s);
    atomicMax(&maxbuf[e * W + c], enc_f(d));
}

// ---- generic scatter: diff = x_dst[d] - x_src[s], segment max into maxbuf ----
__global__ void scatter_diff(const float* __restrict__ xs, const float* __restrict__ xd,
                             const int* __restrict__ isrc, const int* __restrict__ idst,
                             unsigned* __restrict__ maxbuf, int npairs) {
    int t = blockIdx.x * 256 + threadIdx.x;
    int i = t >> 7, c = t & 127;
    if (i >= npairs) return;
    int s = isrc[i], d = idst[i];
    float v = xd[d * W + c] - xs[s * W + c];
    atomicMax(&maxbuf[d * W + c], enc_f(v));
}

// ---- residual MLP update: x += lrelu(concat(x, maxes) @ Wm + bm) ----
// block = 256 threads, 16 rows per block; h staged in LDS.
__global__ __launch_bounds__(256) void conv_update(float* __restrict__ x,
                                                   const unsigned* __restrict__ maxbuf,
                                                   const float* __restrict__ Wm,
                                                   const float* __restrict__ bm, int n) {
    __shared__ float hs[16][256];
    int t = threadIdx.x;
    int r0 = blockIdx.x * 16;
    // stage h = [x_row (128) | maxes (128)] for 16 rows
    for (int idx = t; idx < 16 * 256; idx += 256) {
        int r = idx >> 8, k = idx & 255;
        int row = r0 + r;
        float v = 0.f;
        if (row < n) {
            if (k < 128) {
                v = x[row * W + k];
            } else {
                unsigned e = maxbuf[row * W + (k - 128)];
                v = e ? dec_f(e) : 0.f;
            }
        }
        hs[r][k] = v;
    }
    __syncthreads();
    int c = t & 127, rg = t >> 7;  // all 64 lanes of a wave share rg -> LDS broadcast
    float acc[8];
#pragma unroll
    for (int j = 0; j < 8; j++) acc[j] = 0.f;
    for (int k = 0; k < 256; k += 4) {
        float w0 = Wm[(k + 0) * W + c];
        float w1 = Wm[(k + 1) * W + c];
        float w2 = Wm[(k + 2) * W + c];
        float w3 = Wm[(k + 3) * W + c];
#pragma unroll
        for (int j = 0; j < 8; j++) {
            const float4 h4 = *(const float4*)&hs[rg * 8 + j][k];
            acc[j] += h4.x * w0 + h4.y * w1 + h4.z * w2 + h4.w * w3;
        }
    }
    float bc = bm[c];
#pragma unroll
    for (int j = 0; j < 8; j++) {
        int row = r0 + rg * 8 + j;
        if (row < n) {
            float res = hs[rg * 8 + j][c];  // original x value (c < 128)
            x[row * W + c] = res + lrelu(acc[j] + bc);
        }
    }
}

extern "C" void kernel_launch(void* const* d_in, const int* in_sizes, int n_in,
                              void* d_out, int out_size, void* d_ws, size_t ws_size,
                              hipStream_t stream) {
    const float* vertices = (const float*)d_in[0];
    const float* edges    = (const float*)d_in[1];
    const float* faces    = (const float*)d_in[2];
    const int* etv_v   = (const int*)d_in[3];
    const int* etv_e   = (const int*)d_in[4];
    const int* fte_e   = (const int*)d_in[5];
    const int* fte_f   = (const int*)d_in[6];
    const int* ftf_src = (const int*)d_in[7];
    const int* ftf_dst = (const int*)d_in[8];
    const float* Wv   = (const float*)d_in[9];
    const float* bv   = (const float*)d_in[10];
    const float* We   = (const float*)d_in[11];
    const float* be   = (const float*)d_in[12];
    const float* Wf   = (const float*)d_in[13];
    const float* bf   = (const float*)d_in[14];
    const float* Wv2e = (const float*)d_in[15];
    const float* bv2e = (const float*)d_in[16];
    const float* We2f = (const float*)d_in[17];
    const float* be2f = (const float*)d_in[18];
    const float* Wm0  = (const float*)d_in[19];
    const float* bm0  = (const float*)d_in[20];
    const float* Wm1  = (const float*)d_in[21];
    const float* bm1  = (const float*)d_in[22];

    const int NV = in_sizes[0] / 3;
    const int NE = in_sizes[1] / 12;
    const int NF = in_sizes[2] / 14;
    const int N_EV = in_sizes[3];
    const int N_FE = in_sizes[5];
    const int N_FF = in_sizes[7];
    (void)NV; (void)ws_size; (void)n_in; (void)out_size;

    float* x_e = (float*)d_ws;                                    // NE*128 floats
    unsigned* maxbuf = (unsigned*)(x_e + (size_t)NE * W);         // max(NE,NF)*128 uints
    float* x_f = (float*)d_out;                                   // NF*128 floats

    const int TB = 256;
    // embeds (x_v is folded into scatter_v2e)
    embed_kernel<12><<<((size_t)NE * W + TB - 1) / TB, TB, 0, stream>>>(edges, We, be, x_e, NE);
    embed_kernel<14><<<((size_t)NF * W + TB - 1) / TB, TB, 0, stream>>>(faces, Wf, bf, x_f, NF);

    // conv1: V2E  (dst = edges)
    hipMemsetAsync(maxbuf, 0, (size_t)NE * W * sizeof(unsigned), stream);
    scatter_v2e<<<((size_t)N_EV * W + TB - 1) / TB, TB, 0, stream>>>(vertices, Wv, bv, x_e,
                                                                     etv_v, etv_e, maxbuf, N_EV);
    conv_update<<<(NE + 15) / 16, TB, 0, stream>>>(x_e, maxbuf, Wv2e, bv2e, NE);

    // conv2: E2F  (dst = faces)
    hipMemsetAsync(maxbuf, 0, (size_t)NF * W * sizeof(unsigned), stream);
    scatter_diff<<<((size_t)N_FE * W + TB - 1) / TB, TB, 0, stream>>>(x_e, x_f, fte_e, fte_f,
                                                                      maxbuf, N_FE);
    conv_update<<<(NF + 15) / 16, TB, 0, stream>>>(x_f, maxbuf, We2f, be2f, NF);

    // conv3: F2F message layer 0
    hipMemsetAsync(maxbuf, 0, (size_t)NF * W * sizeof(unsigned), stream);
    scatter_diff<<<((size_t)N_FF * W + TB - 1) / TB, TB, 0, stream>>>(x_f, x_f, ftf_src, ftf_dst,
                                                                      maxbuf, N_FF);
    conv_update<<<(NF + 15) / 16, TB, 0, stream>>>(x_f, maxbuf, Wm0, bm0, NF);

    // conv4: F2F message layer 1
    hipMemsetAsync(maxbuf, 0, (size_t)NF * W * sizeof(unsigned), stream);
    scatter_diff<<<((size_t)N_FF * W + TB - 1) / TB, TB, 0, stream>>>(x_f, x_f, ftf_src, ftf_dst,
                                                                      maxbuf, N_FF);
    conv_update<<<(NF + 15) / 16, TB, 0, stream>>>(x_f, maxbuf, Wm1, bm1, NF);
}

// Round 3
// 1151.107 us; speedup vs baseline: 1.9418x; 1.9418x over previous
//
#include <hip/hip_runtime.h>

#define W 128
#define ROWS 32      // dst rows per block in fused_conv
#define HSTRIDE 264  // bf16 elems per h row (256 + 8 pad -> 2-way-free LDS banking)

typedef short bf16x8 __attribute__((ext_vector_type(8)));
typedef float f32x4 __attribute__((ext_vector_type(4)));

__device__ __forceinline__ float lrelu(float x) { return x > 0.f ? x : 0.01f * x; }

// RTNE float -> bf16 (as ushort bit pattern)
__device__ __forceinline__ unsigned short f2bf(float f) {
    unsigned u = __float_as_uint(f);
    u += 0x7fffu + ((u >> 16) & 1u);
    return (unsigned short)(u >> 16);
}

// ---- initial embed: out[row,c] = lrelu(b[c] + sum_k in[row,k]*Wt[k,c]) ----
template <int K>
__global__ void embed_kernel(const float* __restrict__ in, const float* __restrict__ Wt,
                             const float* __restrict__ bias, float* __restrict__ out, int n) {
    int t = blockIdx.x * 256 + threadIdx.x;
    int row = t >> 7, c = t & 127;
    if (row >= n) return;
    float s = bias[c];
#pragma unroll
    for (int k = 0; k < K; k++) s += in[row * K + k] * Wt[k * W + c];
    out[row * W + c] = lrelu(s);
}

// ---- weight convert: Wm fp32 [256][128] -> Wt bf16 [128][256] (transposed) ----
__global__ void wconv_kernel(const float* __restrict__ Wm, unsigned short* __restrict__ Wt) {
    int i = blockIdx.x * 256 + threadIdx.x;  // 32768 total
    int k = i >> 7, n = i & 127;
    Wt[n * 256 + k] = f2bf(Wm[k * W + n]);
}

// ---- CSR build ----
__global__ void hist_kernel(const int* __restrict__ dst, int np, int* __restrict__ cnt) {
    int i = blockIdx.x * 256 + threadIdx.x;
    if (i < np) atomicAdd(&cnt[dst[i]], 1);
}

__global__ void fill_kernel(const int* __restrict__ dst, const int* __restrict__ src, int np,
                            int* __restrict__ cursor, int* __restrict__ col) {
    int i = blockIdx.x * 256 + threadIdx.x;
    if (i < np) {
        int p = atomicAdd(&cursor[dst[i]], 1);
        col[p] = src[i];
    }
}

// 3-pass exclusive scan: pass1 block-sums of 1024-chunks, pass2 scan sums, pass3 final.
__global__ void scan_pass1(const int* __restrict__ cnt, int n, int* __restrict__ bsum) {
    __shared__ int s[256];
    int b = blockIdx.x, t = threadIdx.x;
    int base = b * 1024;
    int sum = 0;
#pragma unroll
    for (int i = 0; i < 4; i++) {
        int idx = base + t * 4 + i;
        if (idx < n) sum += cnt[idx];
    }
    s[t] = sum;
    __syncthreads();
    for (int off = 128; off > 0; off >>= 1) {
        if (t < off) s[t] += s[t + off];
        __syncthreads();
    }
    if (t == 0) bsum[b] = s[0];
}

__global__ void scan_pass2(int* __restrict__ bsum, int nb) {
    __shared__ int s[1024];
    int t = threadIdx.x;
    int v = (t < nb) ? bsum[t] : 0;
    s[t] = v;
    __syncthreads();
    for (int off = 1; off < 1024; off <<= 1) {
        int add = (t >= off) ? s[t - off] : 0;
        __syncthreads();
        s[t] += add;
        __syncthreads();
    }
    if (t < nb) bsum[t] = s[t] - v;  // exclusive
}

__global__ void scan_pass3(const int* __restrict__ cnt, int n, const int* __restrict__ bsum,
                           int* __restrict__ rowptr, int* __restrict__ cursor, int total) {
    __shared__ int s[256];
    int b = blockIdx.x, t = threadIdx.x;
    int base = b * 1024;
    int v[4];
    int sum = 0;
#pragma unroll
    for (int i = 0; i < 4; i++) {
        int idx = base + t * 4 + i;
        v[i] = (idx < n) ? cnt[idx] : 0;
        sum += v[i];
    }
    s[t] = sum;
    __syncthreads();
    int own = sum;
    for (int off = 1; off < 256; off <<= 1) {
        int add = (t >= off) ? s[t - off] : 0;
        __syncthreads();
        s[t] += add;
        __syncthreads();
    }
    int run = bsum[b] + s[t] - own;
#pragma unroll
    for (int i = 0; i < 4; i++) {
        int idx = base + t * 4 + i;
        if (idx < n) {
            rowptr[idx] = run;
            cursor[idx] = run;
            run += v[i];
        }
    }
    if (b == 0 && t == 0) rowptr[n] = total;
}

// ---- fused conv: gather-min -> h (LDS, bf16) -> MFMA MLP -> residual write ----
// max_j(xd - xs_j) == xd - min_j(xs_j); empty segment -> 0.
// block = 256 (4 waves), 32 dst rows per block.
__global__ __launch_bounds__(256) void fused_conv(
    const float* __restrict__ xs, const float* __restrict__ xd, float* __restrict__ xout,
    const int* __restrict__ rowptr, const int* __restrict__ colidx,
    const unsigned short* __restrict__ Wt, const float* __restrict__ bias, int n_dst) {
    __shared__ unsigned short h[ROWS][HSTRIDE];
    int wave = threadIdx.x >> 6, lane = threadIdx.x & 63;
    int r0 = blockIdx.x * ROWS;

    // --- gather phase: wave handles rows wave*8 .. wave*8+7, lane handles ch 2*lane,2*lane+1
    for (int rr = 0; rr < 8; rr++) {
        int r = wave * 8 + rr;
        int d = r0 + r;
        float2 xdv = make_float2(0.f, 0.f);
        float2 mn = make_float2(3.4e38f, 3.4e38f);
        int deg = 0;
        if (d < n_dst) {
            xdv = *(const float2*)&xd[(size_t)d * W + 2 * lane];
            int beg = rowptr[d], end = rowptr[d + 1];
            deg = end - beg;
            for (int j = beg; j < end; j++) {
                int sidx = colidx[j];
                float2 v = *(const float2*)&xs[(size_t)sidx * W + 2 * lane];
                mn.x = fminf(mn.x, v.x);
                mn.y = fminf(mn.y, v.y);
            }
        }
        float2 mx;
        mx.x = deg ? (xdv.x - mn.x) : 0.f;
        mx.y = deg ? (xdv.y - mn.y) : 0.f;
        ushort2* p0 = (ushort2*)&h[r][2 * lane];
        ushort2* p1 = (ushort2*)&h[r][128 + 2 * lane];
        *p0 = make_ushort2(f2bf(xdv.x), f2bf(xdv.y));
        *p1 = make_ushort2(f2bf(mx.x), f2bf(mx.y));
    }
    __syncthreads();

    // --- MFMA phase: wave -> row-tile rt (16 rows), 4 col-tiles of 16
    int rt = wave >> 1;
    int ctbase = (wave & 1) * 4;
    int m = lane & 15, q = lane >> 4;
    f32x4 acc[4];
#pragma unroll
    for (int ct = 0; ct < 4; ct++) acc[ct] = (f32x4){0.f, 0.f, 0.f, 0.f};

    for (int k0 = 0; k0 < 256; k0 += 32) {
        bf16x8 a = *(const bf16x8*)&h[rt * 16 + m][k0 + q * 8];
#pragma unroll
        for (int ct = 0; ct < 4; ct++) {
            int n = (ctbase + ct) * 16 + m;
            bf16x8 b = *(const bf16x8*)&Wt[n * 256 + k0 + q * 8];
            acc[ct] = __builtin_amdgcn_mfma_f32_16x16x32_bf16(a, b, acc[ct], 0, 0, 0);
        }
    }

    // --- epilogue: D[row=q*4+reg][col=m] per 16x16 tile; residual + lrelu
#pragma unroll
    for (int ct = 0; ct < 4; ct++) {
        int col = (ctbase + ct) * 16 + m;
        float bc = bias[col];
#pragma unroll
        for (int reg = 0; reg < 4; reg++) {
            int row = r0 + rt * 16 + q * 4 + reg;
            if (row < n_dst) {
                float xold = xd[(size_t)row * W + col];
                xout[(size_t)row * W + col] = xold + lrelu(acc[ct][reg] + bc);
            }
        }
    }
}

static inline char* align16(char* p) {
    return (char*)(((uintptr_t)p + 15) & ~(uintptr_t)15);
}

extern "C" void kernel_launch(void* const* d_in, const int* in_sizes, int n_in,
                              void* d_out, int out_size, void* d_ws, size_t ws_size,
                              hipStream_t stream) {
    const float* vertices = (const float*)d_in[0];
    const float* edges    = (const float*)d_in[1];
    const float* faces    = (const float*)d_in[2];
    const int* etv_v   = (const int*)d_in[3];
    const int* etv_e   = (const int*)d_in[4];
    const int* fte_e   = (const int*)d_in[5];
    const int* fte_f   = (const int*)d_in[6];
    const int* ftf_src = (const int*)d_in[7];
    const int* ftf_dst = (const int*)d_in[8];
    const float* Wv   = (const float*)d_in[9];
    const float* bv   = (const float*)d_in[10];
    const float* We   = (const float*)d_in[11];
    const float* be   = (const float*)d_in[12];
    const float* Wf   = (const float*)d_in[13];
    const float* bf_  = (const float*)d_in[14];
    const float* Wv2e = (const float*)d_in[15];
    const float* bv2e = (const float*)d_in[16];
    const float* We2f = (const float*)d_in[17];
    const float* be2f = (const float*)d_in[18];
    const float* Wm0  = (const float*)d_in[19];
    const float* bm0  = (const float*)d_in[20];
    const float* Wm1  = (const float*)d_in[21];
    const float* bm1  = (const float*)d_in[22];

    const int NV = in_sizes[0] / 3;
    const int NE = in_sizes[1] / 12;
    const int NF = in_sizes[2] / 14;
    const int N_EV = in_sizes[3];
    const int N_FE = in_sizes[5];
    const int N_FF = in_sizes[7];
    (void)n_in; (void)out_size; (void)ws_size;

    const int NVF = (NV > NF) ? NV : NF;
    const int NMAX = (NE > NF) ? NE : NF;

    // ---- ws layout ----
    char* p = (char*)d_ws;
    float* x_e = (float*)p;               p += (size_t)NE * W * sizeof(float);
    float* x_v = (float*)p;               p += (size_t)NVF * W * sizeof(float);  // reused as f1
    float* f1 = x_v;
    int* rp_etv = (int*)p;                p += (size_t)(NE + 1) * sizeof(int);
    int* ci_etv = (int*)p;                p += (size_t)N_EV * sizeof(int);
    int* rp_fte = (int*)p;                p += (size_t)(NF + 1) * sizeof(int);
    int* ci_fte = (int*)p;                p += (size_t)N_FE * sizeof(int);
    int* rp_ftf = (int*)p;                p += (size_t)(NF + 1) * sizeof(int);
    int* ci_ftf = (int*)p;                p += (size_t)N_FF * sizeof(int);
    int* cursor = (int*)p;                p += (size_t)(NMAX + 1) * sizeof(int);
    int* bsum   = (int*)p;                p += 1024 * sizeof(int);
    p = align16(p);
    unsigned short* Wt0 = (unsigned short*)p;  p += (size_t)32768 * sizeof(unsigned short);
    unsigned short* Wt1 = (unsigned short*)p;  p += (size_t)32768 * sizeof(unsigned short);
    unsigned short* Wt2 = (unsigned short*)p;  p += (size_t)32768 * sizeof(unsigned short);
    unsigned short* Wt3 = (unsigned short*)p;  p += (size_t)32768 * sizeof(unsigned short);

    float* f0 = (float*)d_out;  // x_f lives in d_out (f0)

    const int TB = 256;

    // ---- embeds ----
    embed_kernel<3><<<((size_t)NV * W + TB - 1) / TB, TB, 0, stream>>>(vertices, Wv, bv, x_v, NV);
    embed_kernel<12><<<((size_t)NE * W + TB - 1) / TB, TB, 0, stream>>>(edges, We, be, x_e, NE);
    embed_kernel<14><<<((size_t)NF * W + TB - 1) / TB, TB, 0, stream>>>(faces, Wf, bf_, f0, NF);

    // ---- weight converts ----
    wconv_kernel<<<128, TB, 0, stream>>>(Wv2e, Wt0);
    wconv_kernel<<<128, TB, 0, stream>>>(We2f, Wt1);
    wconv_kernel<<<128, TB, 0, stream>>>(Wm0, Wt2);
    wconv_kernel<<<128, TB, 0, stream>>>(Wm1, Wt3);

    // ---- CSR builds ----
    struct CsrJob { const int* dst; const int* src; int np; int n; int* rp; int* ci; };
    CsrJob jobs[3] = {
        {etv_e, etv_v, N_EV, NE, rp_etv, ci_etv},
        {fte_f, fte_e, N_FE, NF, rp_fte, ci_fte},
        {ftf_dst, ftf_src, N_FF, NF, rp_ftf, ci_ftf},
    };
    for (int jj = 0; jj < 3; jj++) {
        CsrJob& J = jobs[jj];
        int nb = (J.n + 1023) / 1024;
        (void)hipMemsetAsync(cursor, 0, (size_t)(J.n + 1) * sizeof(int), stream);
        hist_kernel<<<(J.np + TB - 1) / TB, TB, 0, stream>>>(J.dst, J.np, cursor);
        scan_pass1<<<nb, TB, 0, stream>>>(cursor, J.n, bsum);
        scan_pass2<<<1, 1024, 0, stream>>>(bsum, nb);
        scan_pass3<<<nb, TB, 0, stream>>>(cursor, J.n, bsum, J.rp, cursor, J.np);
        fill_kernel<<<(J.np + TB - 1) / TB, TB, 0, stream>>>(J.dst, J.src, J.np, cursor, J.ci);
    }

    // ---- fused convs ----
    // conv1: V2E, src=x_v, dst=x_e in-place
    fused_conv<<<(NE + ROWS - 1) / ROWS, TB, 0, stream>>>(x_v, x_e, x_e, rp_etv, ci_etv, Wt0, bv2e, NE);
    // conv2: E2F, src=x_e, dst=f0 (d_out) in-place
    fused_conv<<<(NF + ROWS - 1) / ROWS, TB, 0, stream>>>(x_e, f0, f0, rp_fte, ci_fte, Wt1, be2f, NF);
    // conv3: F2F layer0, f0 -> f1 (ping-pong; self-referencing src)
    fused_conv<<<(NF + ROWS - 1) / ROWS, TB, 0, stream>>>(f0, f0, f1, rp_ftf, ci_ftf, Wt2, bm0, NF);
    // conv4: F2F layer1, f1 -> d_out
    fused_conv<<<(NF + ROWS - 1) / ROWS, TB, 0, stream>>>(f1, f1, f0, rp_ftf, ci_ftf, Wt3, bm1, NF);
}

// Round 4
// 1056.159 us; speedup vs baseline: 2.1164x; 1.0899x over previous
//
#include <hip/hip_runtime.h>

#define W 128
#define ROWS 32      // dst rows per block in fused_conv
#define HSTRIDE 264  // bf16 elems per h row (256 + 8 pad)

typedef short bf16x8 __attribute__((ext_vector_type(8)));
typedef float f32x4 __attribute__((ext_vector_type(4)));

__device__ __forceinline__ float lrelu(float x) { return x > 0.f ? x : 0.01f * x; }

// RTNE float -> bf16 (as ushort bit pattern)
__device__ __forceinline__ unsigned short f2bf(float f) {
    unsigned u = __float_as_uint(f);
    u += 0x7fffu + ((u >> 16) & 1u);
    return (unsigned short)(u >> 16);
}

__device__ __forceinline__ float4 min4(float4 a, float4 b) {
    return make_float4(fminf(a.x, b.x), fminf(a.y, b.y), fminf(a.z, b.z), fminf(a.w, b.w));
}

// ---- initial embed: out[row,c] = lrelu(b[c] + sum_k in[row,k]*Wt[k,c]) ----
template <int K>
__global__ void embed_kernel(const float* __restrict__ in, const float* __restrict__ Wt,
                             const float* __restrict__ bias, float* __restrict__ out, int n) {
    int t = blockIdx.x * 256 + threadIdx.x;
    int row = t >> 7, c = t & 127;
    if (row >= n) return;
    float s = bias[c];
#pragma unroll
    for (int k = 0; k < K; k++) s += in[row * K + k] * Wt[k * W + c];
    out[row * W + c] = lrelu(s);
}

// ---- fused weight convert: 4x [256][128] fp32 -> [128][256] bf16 transposed ----
__global__ void wconv4_kernel(const float* __restrict__ W0, const float* __restrict__ W1,
                              const float* __restrict__ W2, const float* __restrict__ W3,
                              unsigned short* __restrict__ T0, unsigned short* __restrict__ T1,
                              unsigned short* __restrict__ T2, unsigned short* __restrict__ T3) {
    int which = blockIdx.x >> 7;
    const float* Wm = (which == 0) ? W0 : (which == 1) ? W1 : (which == 2) ? W2 : W3;
    unsigned short* Wt = (which == 0) ? T0 : (which == 1) ? T1 : (which == 2) ? T2 : T3;
    int i = (blockIdx.x & 127) * 256 + threadIdx.x;  // 32768 per matrix
    int k = i >> 7, n = i & 127;
    Wt[n * 256 + k] = f2bf(Wm[k * W + n]);
}

// ---- fused CSR build over 3 concatenated jobs ----
__global__ void hist3_kernel(const int* __restrict__ d0, int n0, const int* __restrict__ d1,
                             int n1, const int* __restrict__ d2, int n2, int* __restrict__ cnt,
                             int off1, int off2) {
    int i = blockIdx.x * 256 + threadIdx.x;
    if (i < n0) atomicAdd(&cnt[d0[i]], 1);
    else if (i < n0 + n1) atomicAdd(&cnt[off1 + d1[i - n0]], 1);
    else if (i < n0 + n1 + n2) atomicAdd(&cnt[off2 + d2[i - n0 - n1]], 1);
}

__global__ void fill3_kernel(const int* __restrict__ d0, const int* __restrict__ s0_, int n0,
                             const int* __restrict__ d1, const int* __restrict__ s1_, int n1,
                             const int* __restrict__ d2, const int* __restrict__ s2_, int n2,
                             int* __restrict__ cursor, int off1, int off2,
                             int* __restrict__ ci) {
    int i = blockIdx.x * 256 + threadIdx.x;
    if (i < n0) {
        int p = atomicAdd(&cursor[d0[i]], 1);
        ci[p] = s0_[i];
    } else if (i < n0 + n1) {
        int j = i - n0;
        int p = atomicAdd(&cursor[off1 + d1[j]], 1);
        ci[p] = s1_[j];
    } else if (i < n0 + n1 + n2) {
        int j = i - n0 - n1;
        int p = atomicAdd(&cursor[off2 + d2[j]], 1);
        ci[p] = s2_[j];
    }
}

// 3-pass exclusive scan over the concatenated count array.
__global__ void scan_pass1(const int* __restrict__ cnt, int n, int* __restrict__ bsum) {
    __shared__ int s[256];
    int b = blockIdx.x, t = threadIdx.x;
    int base = b * 1024;
    int sum = 0;
#pragma unroll
    for (int i = 0; i < 4; i++) {
        int idx = base + t * 4 + i;
        if (idx < n) sum += cnt[idx];
    }
    s[t] = sum;
    __syncthreads();
    for (int off = 128; off > 0; off >>= 1) {
        if (t < off) s[t] += s[t + off];
        __syncthreads();
    }
    if (t == 0) bsum[b] = s[0];
}

__global__ void scan_pass2(int* __restrict__ bsum, int nb) {
    __shared__ int s[1024];
    int t = threadIdx.x;
    int v = (t < nb) ? bsum[t] : 0;
    s[t] = v;
    __syncthreads();
    for (int off = 1; off < 1024; off <<= 1) {
        int add = (t >= off) ? s[t - off] : 0;
        __syncthreads();
        s[t] += add;
        __syncthreads();
    }
    if (t < nb) bsum[t] = s[t] - v;  // exclusive
}

__global__ void scan_pass3(const int* __restrict__ cnt, int n, const int* __restrict__ bsum,
                           int* __restrict__ rowptr, int* __restrict__ cursor) {
    __shared__ int s[256];
    int b = blockIdx.x, t = threadIdx.x;
    int base = b * 1024;
    int v[4];
    int sum = 0;
#pragma unroll
    for (int i = 0; i < 4; i++) {
        int idx = base + t * 4 + i;
        v[i] = (idx < n) ? cnt[idx] : 0;
        sum += v[i];
    }
    s[t] = sum;
    __syncthreads();
    int own = sum;
    for (int off = 1; off < 256; off <<= 1) {
        int add = (t >= off) ? s[t - off] : 0;
        __syncthreads();
        s[t] += add;
        __syncthreads();
    }
    int run = bsum[b] + s[t] - own;
#pragma unroll
    for (int i = 0; i < 4; i++) {
        int idx = base + t * 4 + i;
        if (idx < n) {
            rowptr[idx] = run;
            cursor[idx] = run;
            run += v[i];
        }
    }
}

// ---- fused conv: gather-min (float4, unroll-4, split-halves) -> bf16 h in LDS ->
//      MFMA MLP -> residual write.  max_j(xd - xs_j) == xd - min_j(xs_j).
__global__ __launch_bounds__(256) void fused_conv(
    const float* __restrict__ xs, const float* __restrict__ xd, float* __restrict__ xout,
    const int* __restrict__ rowptr, const int* __restrict__ colidx,
    const unsigned short* __restrict__ Wt, const float* __restrict__ bias, int n_dst) {
    __shared__ unsigned short h[ROWS][HSTRIDE];
    int wave = threadIdx.x >> 6, lane = threadIdx.x & 63;
    int li = lane & 31, half = lane >> 5;
    int r0 = blockIdx.x * ROWS;
    const float4* xs4 = (const float4*)xs;
    const float4* xd4 = (const float4*)xd;

    // gather: wave handles rows wave*8..+7; 32 lanes x float4 cover one 128-ch row;
    // the two halves take alternating neighbors (stride 2), each unrolled x4.
    for (int rr = 0; rr < 8; rr++) {
        int r = wave * 8 + rr;
        int d = r0 + r;
        float4 xdv = make_float4(0.f, 0.f, 0.f, 0.f);
        float4 mn = make_float4(3.4e38f, 3.4e38f, 3.4e38f, 3.4e38f);
        int deg = 0;
        if (d < n_dst) {
            int beg = rowptr[d], end = rowptr[d + 1];
            deg = end - beg;
            if (half == 0) xdv = xd4[(size_t)d * 32 + li];
            int j = beg + half;
            while (j + 6 < end) {  // 4 neighbors in flight
                int s0 = colidx[j], s1 = colidx[j + 2], s2 = colidx[j + 4], s3 = colidx[j + 6];
                float4 v0 = xs4[(size_t)s0 * 32 + li];
                float4 v1 = xs4[(size_t)s1 * 32 + li];
                float4 v2 = xs4[(size_t)s2 * 32 + li];
                float4 v3 = xs4[(size_t)s3 * 32 + li];
                mn = min4(mn, min4(min4(v0, v1), min4(v2, v3)));
                j += 8;
            }
            while (j + 2 < end) {  // 2 neighbors in flight
                int s0 = colidx[j], s1 = colidx[j + 2];
                float4 v0 = xs4[(size_t)s0 * 32 + li];
                float4 v1 = xs4[(size_t)s1 * 32 + li];
                mn = min4(mn, min4(v0, v1));
                j += 4;
            }
            if (j < end) {
                int s0 = colidx[j];
                mn = min4(mn, xs4[(size_t)s0 * 32 + li]);
            }
        }
        // combine the two halves' partial mins; broadcast xdv from half 0
        mn.x = fminf(mn.x, __shfl_xor(mn.x, 32));
        mn.y = fminf(mn.y, __shfl_xor(mn.y, 32));
        mn.z = fminf(mn.z, __shfl_xor(mn.z, 32));
        mn.w = fminf(mn.w, __shfl_xor(mn.w, 32));
        xdv.x = __shfl(xdv.x, li);
        xdv.y = __shfl(xdv.y, li);
        xdv.z = __shfl(xdv.z, li);
        xdv.w = __shfl(xdv.w, li);
        float4 mx;
        mx.x = deg ? (xdv.x - mn.x) : 0.f;
        mx.y = deg ? (xdv.y - mn.y) : 0.f;
        mx.z = deg ? (xdv.z - mn.z) : 0.f;
        mx.w = deg ? (xdv.w - mn.w) : 0.f;
        if (half == 0) {
            *(ushort4*)&h[r][li * 4] =
                make_ushort4(f2bf(xdv.x), f2bf(xdv.y), f2bf(xdv.z), f2bf(xdv.w));
        } else {
            *(ushort4*)&h[r][128 + li * 4] =
                make_ushort4(f2bf(mx.x), f2bf(mx.y), f2bf(mx.z), f2bf(mx.w));
        }
    }
    __syncthreads();

    // --- MFMA phase: wave -> row-tile rt (16 rows), 4 col-tiles of 16
    int rt = wave >> 1;
    int ctbase = (wave & 1) * 4;
    int m = lane & 15, q = lane >> 4;
    f32x4 acc[4];
#pragma unroll
    for (int ct = 0; ct < 4; ct++) acc[ct] = (f32x4){0.f, 0.f, 0.f, 0.f};

    for (int k0 = 0; k0 < 256; k0 += 32) {
        bf16x8 a = *(const bf16x8*)&h[rt * 16 + m][k0 + q * 8];
#pragma unroll
        for (int ct = 0; ct < 4; ct++) {
            int n = (ctbase + ct) * 16 + m;
            bf16x8 b = *(const bf16x8*)&Wt[n * 256 + k0 + q * 8];
            acc[ct] = __builtin_amdgcn_mfma_f32_16x16x32_bf16(a, b, acc[ct], 0, 0, 0);
        }
    }

    // --- epilogue: D[row=q*4+reg][col=m] per 16x16 tile; residual + lrelu
#pragma unroll
    for (int ct = 0; ct < 4; ct++) {
        int col = (ctbase + ct) * 16 + m;
        float bc = bias[col];
#pragma unroll
        for (int reg = 0; reg < 4; reg++) {
            int row = r0 + rt * 16 + q * 4 + reg;
            if (row < n_dst) {
                float xold = xd[(size_t)row * W + col];
                xout[(size_t)row * W + col] = xold + lrelu(acc[ct][reg] + bc);
            }
        }
    }
}

static inline char* align16(char* p) {
    return (char*)(((uintptr_t)p + 15) & ~(uintptr_t)15);
}

extern "C" void kernel_launch(void* const* d_in, const int* in_sizes, int n_in,
                              void* d_out, int out_size, void* d_ws, size_t ws_size,
                              hipStream_t stream) {
    const float* vertices = (const float*)d_in[0];
    const float* edges    = (const float*)d_in[1];
    const float* faces    = (const float*)d_in[2];
    const int* etv_v   = (const int*)d_in[3];
    const int* etv_e   = (const int*)d_in[4];
    const int* fte_e   = (const int*)d_in[5];
    const int* fte_f   = (const int*)d_in[6];
    const int* ftf_src = (const int*)d_in[7];
    const int* ftf_dst = (const int*)d_in[8];
    const float* Wv   = (const float*)d_in[9];
    const float* bv   = (const float*)d_in[10];
    const float* We   = (const float*)d_in[11];
    const float* be   = (const float*)d_in[12];
    const float* Wf   = (const float*)d_in[13];
    const float* bf_  = (const float*)d_in[14];
    const float* Wv2e = (const float*)d_in[15];
    const float* bv2e = (const float*)d_in[16];
    const float* We2f = (const float*)d_in[17];
    const float* be2f = (const float*)d_in[18];
    const float* Wm0  = (const float*)d_in[19];
    const float* bm0  = (const float*)d_in[20];
    const float* Wm1  = (const float*)d_in[21];
    const float* bm1  = (const float*)d_in[22];

    const int NV = in_sizes[0] / 3;
    const int NE = in_sizes[1] / 12;
    const int NF = in_sizes[2] / 14;
    const int N_EV = in_sizes[3];
    const int N_FE = in_sizes[5];
    const int N_FF = in_sizes[7];
    (void)n_in; (void)out_size; (void)ws_size;

    const int NVF = (NV > NF) ? NV : NF;

    // concatenated CSR layout: [job0: NE cnt + 1 sentinel][job1: NF + 1][job2: NF + 1]
    const int off1 = NE + 1;
    const int off2 = NE + 1 + NF + 1;
    const int NTOT = NE + NF + NF + 3;
    const int NP_TOT = N_EV + N_FE + N_FF;

    // ---- ws layout ----
    char* p = (char*)d_ws;
    float* x_e = (float*)p;               p += (size_t)NE * W * sizeof(float);
    float* x_v = (float*)p;               p += (size_t)NVF * W * sizeof(float);  // reused as f1
    float* f1 = x_v;
    int* cnt_all = (int*)p;               p += (size_t)NTOT * sizeof(int);  // scan input
    int* rp_all  = (int*)p;               p += (size_t)NTOT * sizeof(int);
    int* cur_all = (int*)p;               p += (size_t)NTOT * sizeof(int);
    int* ci_all  = (int*)p;               p += (size_t)NP_TOT * sizeof(int);
    int* bsum    = (int*)p;               p += 1024 * sizeof(int);
    p = align16(p);
    unsigned short* Wt0 = (unsigned short*)p;  p += (size_t)32768 * sizeof(unsigned short);
    unsigned short* Wt1 = (unsigned short*)p;  p += (size_t)32768 * sizeof(unsigned short);
    unsigned short* Wt2 = (unsigned short*)p;  p += (size_t)32768 * sizeof(unsigned short);
    unsigned short* Wt3 = (unsigned short*)p;  p += (size_t)32768 * sizeof(unsigned short);

    float* f0 = (float*)d_out;  // x_f lives in d_out

    const int TB = 256;

    // ---- embeds ----
    embed_kernel<3><<<((size_t)NV * W + TB - 1) / TB, TB, 0, stream>>>(vertices, Wv, bv, x_v, NV);
    embed_kernel<12><<<((size_t)NE * W + TB - 1) / TB, TB, 0, stream>>>(edges, We, be, x_e, NE);
    embed_kernel<14><<<((size_t)NF * W + TB - 1) / TB, TB, 0, stream>>>(faces, Wf, bf_, f0, NF);

    // ---- weight converts (one kernel) ----
    wconv4_kernel<<<512, TB, 0, stream>>>(Wv2e, We2f, Wm0, Wm1, Wt0, Wt1, Wt2, Wt3);

    // ---- CSR build (one fused pipeline over 3 jobs) ----
    (void)hipMemsetAsync(cnt_all, 0, (size_t)NTOT * sizeof(int), stream);
    hist3_kernel<<<(NP_TOT + TB - 1) / TB, TB, 0, stream>>>(etv_e, N_EV, fte_f, N_FE, ftf_dst,
                                                            N_FF, cnt_all, off1, off2);
    int nb = (NTOT + 1023) / 1024;
    scan_pass1<<<nb, TB, 0, stream>>>(cnt_all, NTOT, bsum);
    scan_pass2<<<1, 1024, 0, stream>>>(bsum, nb);
    scan_pass3<<<nb, TB, 0, stream>>>(cnt_all, NTOT, bsum, rp_all, cur_all);
    fill3_kernel<<<(NP_TOT + TB - 1) / TB, TB, 0, stream>>>(etv_e, etv_v, N_EV, fte_f, fte_e,
                                                            N_FE, ftf_dst, ftf_src, N_FF,
                                                            cur_all, off1, off2, ci_all);

    // ---- fused convs ----
    fused_conv<<<(NE + ROWS - 1) / ROWS, TB, 0, stream>>>(x_v, x_e, x_e, rp_all, ci_all, Wt0,
                                                          bv2e, NE);
    fused_conv<<<(NF + ROWS - 1) / ROWS, TB, 0, stream>>>(x_e, f0, f0, rp_all + off1, ci_all,
                                                          Wt1, be2f, NF);
    fused_conv<<<(NF + ROWS - 1) / ROWS, TB, 0, stream>>>(f0, f0, f1, rp_all + off2, ci_all,
                                                          Wt2, bm0, NF);
    fused_conv<<<(NF + ROWS - 1) / ROWS, TB, 0, stream>>>(f1, f1, f0, rp_all + off2, ci_all,
                                                          Wt3, bm1, NF);
}

// Round 5
// 1002.904 us; speedup vs baseline: 2.2288x; 1.0531x over previous
//
#include <hip/hip_runtime.h>

#define W 128
#define ROWS 32      // dst rows per block in fused_conv
#define HSTRIDE 264  // bf16 elems per h row (256 + 8 pad)

typedef short bf16x8 __attribute__((ext_vector_type(8)));
typedef float f32x4 __attribute__((ext_vector_type(4)));

__device__ __forceinline__ float lrelu(float x) { return x > 0.f ? x : 0.01f * x; }

// RTNE float -> bf16 (as ushort bit pattern)
__device__ __forceinline__ unsigned short f2bf(float f) {
    unsigned u = __float_as_uint(f);
    u += 0x7fffu + ((u >> 16) & 1u);
    return (unsigned short)(u >> 16);
}
__device__ __forceinline__ float bfu(unsigned short u) {
    return __uint_as_float(((unsigned)u) << 16);
}
__device__ __forceinline__ float4 bf4_to_f4(ushort4 u) {
    return make_float4(bfu(u.x), bfu(u.y), bfu(u.z), bfu(u.w));
}
__device__ __forceinline__ ushort4 f4_to_bf4(float4 f) {
    return make_ushort4(f2bf(f.x), f2bf(f.y), f2bf(f.z), f2bf(f.w));
}
__device__ __forceinline__ float4 min4(float4 a, float4 b) {
    return make_float4(fminf(a.x, b.x), fminf(a.y, b.y), fminf(a.z, b.z), fminf(a.w, b.w));
}

// ---- initial embed: lrelu(in @ Wm + b) -> fp32 and/or bf16 ----
template <int K, bool OF, bool OB>
__global__ void embed_kernel(const float* __restrict__ in, const float* __restrict__ Wm,
                             const float* __restrict__ bias, float* __restrict__ outf,
                             unsigned short* __restrict__ outb, int n) {
    int t = blockIdx.x * 256 + threadIdx.x;
    int row = t >> 7, c = t & 127;
    if (row >= n) return;
    float s = bias[c];
#pragma unroll
    for (int k = 0; k < K; k++) s += in[row * K + k] * Wm[k * W + c];
    s = lrelu(s);
    if (OF) outf[(size_t)row * W + c] = s;
    if (OB) outb[(size_t)row * W + c] = f2bf(s);
}

// ---- fused weight convert: 4x [256][128] fp32 -> [128][256] bf16 transposed ----
__global__ void wconv4_kernel(const float* __restrict__ W0, const float* __restrict__ W1,
                              const float* __restrict__ W2, const float* __restrict__ W3,
                              unsigned short* __restrict__ T0, unsigned short* __restrict__ T1,
                              unsigned short* __restrict__ T2, unsigned short* __restrict__ T3) {
    int which = blockIdx.x >> 7;
    const float* Wm = (which == 0) ? W0 : (which == 1) ? W1 : (which == 2) ? W2 : W3;
    unsigned short* Wt = (which == 0) ? T0 : (which == 1) ? T1 : (which == 2) ? T2 : T3;
    int i = (blockIdx.x & 127) * 256 + threadIdx.x;  // 32768 per matrix
    int k = i >> 7, n = i & 127;
    Wt[n * 256 + k] = f2bf(Wm[k * W + n]);
}

// ---- fused CSR build over 3 concatenated jobs ----
__global__ void hist3_kernel(const int* __restrict__ d0, int n0, const int* __restrict__ d1,
                             int n1, const int* __restrict__ d2, int n2, int* __restrict__ cnt,
                             int off1, int off2) {
    int i = blockIdx.x * 256 + threadIdx.x;
    if (i < n0) atomicAdd(&cnt[d0[i]], 1);
    else if (i < n0 + n1) atomicAdd(&cnt[off1 + d1[i - n0]], 1);
    else if (i < n0 + n1 + n2) atomicAdd(&cnt[off2 + d2[i - n0 - n1]], 1);
}

__global__ void fill3_kernel(const int* __restrict__ d0, const int* __restrict__ s0_, int n0,
                             const int* __restrict__ d1, const int* __restrict__ s1_, int n1,
                             const int* __restrict__ d2, const int* __restrict__ s2_, int n2,
                             int* __restrict__ cursor, int off1, int off2,
                             int* __restrict__ ci) {
    int i = blockIdx.x * 256 + threadIdx.x;
    if (i < n0) {
        int p = atomicAdd(&cursor[d0[i]], 1);
        ci[p] = s0_[i];
    } else if (i < n0 + n1) {
        int j = i - n0;
        int p = atomicAdd(&cursor[off1 + d1[j]], 1);
        ci[p] = s1_[j];
    } else if (i < n0 + n1 + n2) {
        int j = i - n0 - n1;
        int p = atomicAdd(&cursor[off2 + d2[j]], 1);
        ci[p] = s2_[j];
    }
}

__global__ void scan_pass1(const int* __restrict__ cnt, int n, int* __restrict__ bsum) {
    __shared__ int s[256];
    int b = blockIdx.x, t = threadIdx.x;
    int base = b * 1024;
    int sum = 0;
#pragma unroll
    for (int i = 0; i < 4; i++) {
        int idx = base + t * 4 + i;
        if (idx < n) sum += cnt[idx];
    }
    s[t] = sum;
    __syncthreads();
    for (int off = 128; off > 0; off >>= 1) {
        if (t < off) s[t] += s[t + off];
        __syncthreads();
    }
    if (t == 0) bsum[b] = s[0];
}

__global__ void scan_pass2(int* __restrict__ bsum, int nb) {
    __shared__ int s[1024];
    int t = threadIdx.x;
    int v = (t < nb) ? bsum[t] : 0;
    s[t] = v;
    __syncthreads();
    for (int off = 1; off < 1024; off <<= 1) {
        int add = (t >= off) ? s[t - off] : 0;
        __syncthreads();
        s[t] += add;
        __syncthreads();
    }
    if (t < nb) bsum[t] = s[t] - v;  // exclusive
}

__global__ void scan_pass3(const int* __restrict__ cnt, int n, const int* __restrict__ bsum,
                           int* __restrict__ rowptr, int* __restrict__ cursor) {
    __shared__ int s[256];
    int b = blockIdx.x, t = threadIdx.x;
    int base = b * 1024;
    int v[4];
    int sum = 0;
#pragma unroll
    for (int i = 0; i < 4; i++) {
        int idx = base + t * 4 + i;
        v[i] = (idx < n) ? cnt[idx] : 0;
        sum += v[i];
    }
    s[t] = sum;
    __syncthreads();
    int own = sum;
    for (int off = 1; off < 256; off <<= 1) {
        int add = (t >= off) ? s[t - off] : 0;
        __syncthreads();
        s[t] += add;
        __syncthreads();
    }
    int run = bsum[b] + s[t] - own;
#pragma unroll
    for (int i = 0; i < 4; i++) {
        int idx = base + t * 4 + i;
        if (idx < n) {
            rowptr[idx] = run;
            cursor[idx] = run;
            run += v[i];
        }
    }
}

// ---- fused conv: bf16 gather-min -> bf16 h in LDS -> MFMA MLP -> residual write ----
// max_j(xd - xs_j) == xd - min_j(xs_j); empty segment -> 0.
// block = 256 (4 waves). Each 32-lane half owns one dst row at a time (4 rows each);
// lane li owns channels [4*li, 4*li+3] (8B bf16 loads). No cross-lane combine needed.
template <bool XD_BF, bool OUT_F32, bool OUT_BF>
__global__ __launch_bounds__(256) void fused_conv(
    const unsigned short* __restrict__ xsb, const float* __restrict__ xd_f,
    const unsigned short* __restrict__ xd_b, float* __restrict__ out_f,
    unsigned short* __restrict__ out_b, const int* __restrict__ rowptr,
    const int* __restrict__ colidx, const unsigned short* __restrict__ Wt,
    const float* __restrict__ bias, int n_dst) {
    __shared__ unsigned short h[ROWS][HSTRIDE];
    int wave = threadIdx.x >> 6, lane = threadIdx.x & 63;
    int li = lane & 31, half = lane >> 5;
    int r0 = blockIdx.x * ROWS;
    const ushort4* xs4 = (const ushort4*)xsb;

    int rbase = wave * 8 + half * 4;
    for (int rr = 0; rr < 4; rr++) {
        int r = rbase + rr;
        int d = r0 + r;
        float4 xdv = make_float4(0.f, 0.f, 0.f, 0.f);
        ushort4 xdu = make_ushort4(0, 0, 0, 0);
        float4 mn = make_float4(3.4e38f, 3.4e38f, 3.4e38f, 3.4e38f);
        int deg = 0;
        if (d < n_dst) {
            int beg = rowptr[d], end = rowptr[d + 1];
            deg = end - beg;
            if (XD_BF) {
                xdu = ((const ushort4*)xd_b)[(size_t)d * 32 + li];
                xdv = bf4_to_f4(xdu);
            } else {
                xdv = ((const float4*)xd_f)[(size_t)d * 32 + li];
            }
            int j = beg;
            while (j + 8 <= end) {  // 8 row-reads in flight per half-wave
                int s0 = colidx[j], s1 = colidx[j + 1], s2 = colidx[j + 2], s3 = colidx[j + 3];
                int s4 = colidx[j + 4], s5 = colidx[j + 5], s6 = colidx[j + 6], s7 = colidx[j + 7];
                ushort4 v0 = xs4[(size_t)s0 * 32 + li];
                ushort4 v1 = xs4[(size_t)s1 * 32 + li];
                ushort4 v2 = xs4[(size_t)s2 * 32 + li];
                ushort4 v3 = xs4[(size_t)s3 * 32 + li];
                ushort4 v4 = xs4[(size_t)s4 * 32 + li];
                ushort4 v5 = xs4[(size_t)s5 * 32 + li];
                ushort4 v6 = xs4[(size_t)s6 * 32 + li];
                ushort4 v7 = xs4[(size_t)s7 * 32 + li];
                float4 m01 = min4(bf4_to_f4(v0), bf4_to_f4(v1));
                float4 m23 = min4(bf4_to_f4(v2), bf4_to_f4(v3));
                float4 m45 = min4(bf4_to_f4(v4), bf4_to_f4(v5));
                float4 m67 = min4(bf4_to_f4(v6), bf4_to_f4(v7));
                mn = min4(mn, min4(min4(m01, m23), min4(m45, m67)));
                j += 8;
            }
            while (j + 2 <= end) {
                int s0 = colidx[j], s1 = colidx[j + 1];
                ushort4 v0 = xs4[(size_t)s0 * 32 + li];
                ushort4 v1 = xs4[(size_t)s1 * 32 + li];
                mn = min4(mn, min4(bf4_to_f4(v0), bf4_to_f4(v1)));
                j += 2;
            }
            if (j < end) {
                int s0 = colidx[j];
                mn = min4(mn, bf4_to_f4(xs4[(size_t)s0 * 32 + li]));
            }
        }
        float4 mx;
        mx.x = deg ? (xdv.x - mn.x) : 0.f;
        mx.y = deg ? (xdv.y - mn.y) : 0.f;
        mx.z = deg ? (xdv.z - mn.z) : 0.f;
        mx.w = deg ? (xdv.w - mn.w) : 0.f;
        *(ushort4*)&h[r][li * 4] = XD_BF ? xdu : f4_to_bf4(xdv);
        *(ushort4*)&h[r][128 + li * 4] = f4_to_bf4(mx);
    }
    __syncthreads();

    // --- MFMA phase: wave -> row-tile rt (16 rows), 4 col-tiles of 16
    int rt = wave >> 1;
    int ctbase = (wave & 1) * 4;
    int m = lane & 15, q = lane >> 4;
    f32x4 acc[4];
#pragma unroll
    for (int ct = 0; ct < 4; ct++) acc[ct] = (f32x4){0.f, 0.f, 0.f, 0.f};

    for (int k0 = 0; k0 < 256; k0 += 32) {
        bf16x8 a = *(const bf16x8*)&h[rt * 16 + m][k0 + q * 8];
#pragma unroll
        for (int ct = 0; ct < 4; ct++) {
            int n = (ctbase + ct) * 16 + m;
            bf16x8 b = *(const bf16x8*)&Wt[n * 256 + k0 + q * 8];
            acc[ct] = __builtin_amdgcn_mfma_f32_16x16x32_bf16(a, b, acc[ct], 0, 0, 0);
        }
    }

    // --- epilogue: D[row=q*4+reg][col=m] per 16x16 tile; residual + lrelu
#pragma unroll
    for (int ct = 0; ct < 4; ct++) {
        int col = (ctbase + ct) * 16 + m;
        float bc = bias[col];
#pragma unroll
        for (int reg = 0; reg < 4; reg++) {
            int row = r0 + rt * 16 + q * 4 + reg;
            if (row < n_dst) {
                float xold = XD_BF ? bfu(xd_b[(size_t)row * W + col])
                                   : xd_f[(size_t)row * W + col];
                float val = xold + lrelu(acc[ct][reg] + bc);
                if (OUT_F32) out_f[(size_t)row * W + col] = val;
                if (OUT_BF) out_b[(size_t)row * W + col] = f2bf(val);
            }
        }
    }
}

static inline char* align16(char* p) {
    return (char*)(((uintptr_t)p + 15) & ~(uintptr_t)15);
}

extern "C" void kernel_launch(void* const* d_in, const int* in_sizes, int n_in,
                              void* d_out, int out_size, void* d_ws, size_t ws_size,
                              hipStream_t stream) {
    const float* vertices = (const float*)d_in[0];
    const float* edges    = (const float*)d_in[1];
    const float* faces    = (const float*)d_in[2];
    const int* etv_v   = (const int*)d_in[3];
    const int* etv_e   = (const int*)d_in[4];
    const int* fte_e   = (const int*)d_in[5];
    const int* fte_f   = (const int*)d_in[6];
    const int* ftf_src = (const int*)d_in[7];
    const int* ftf_dst = (const int*)d_in[8];
    const float* Wv   = (const float*)d_in[9];
    const float* bv   = (const float*)d_in[10];
    const float* We   = (const float*)d_in[11];
    const float* be   = (const float*)d_in[12];
    const float* Wf   = (const float*)d_in[13];
    const float* bf_  = (const float*)d_in[14];
    const float* Wv2e = (const float*)d_in[15];
    const float* bv2e = (const float*)d_in[16];
    const float* We2f = (const float*)d_in[17];
    const float* be2f = (const float*)d_in[18];
    const float* Wm0  = (const float*)d_in[19];
    const float* bm0  = (const float*)d_in[20];
    const float* Wm1  = (const float*)d_in[21];
    const float* bm1  = (const float*)d_in[22];

    const int NV = in_sizes[0] / 3;
    const int NE = in_sizes[1] / 12;
    const int NF = in_sizes[2] / 14;
    const int N_EV = in_sizes[3];
    const int N_FE = in_sizes[5];
    const int N_FF = in_sizes[7];
    (void)n_in; (void)out_size; (void)ws_size;

    // concatenated CSR layout: [job0: NE cnt + 1 sentinel][job1: NF + 1][job2: NF + 1]
    const int off1 = NE + 1;
    const int off2 = NE + 1 + NF + 1;
    const int NTOT = NE + NF + NF + 3;
    const int NP_TOT = N_EV + N_FE + N_FF;

    // ---- ws layout (~192 MB) ----
    char* p = (char*)d_ws;
    unsigned short* x_vb = (unsigned short*)p;  p += (size_t)NV * W * sizeof(unsigned short);
    unsigned short* x_eb = (unsigned short*)p;  p += (size_t)NE * W * sizeof(unsigned short);
    unsigned short* f0b  = (unsigned short*)p;  p += (size_t)NF * W * sizeof(unsigned short);
    unsigned short* f1b  = (unsigned short*)p;  p += (size_t)NF * W * sizeof(unsigned short);
    p = align16(p);
    float* f1 = (float*)p;                      p += (size_t)NF * W * sizeof(float);
    int* cnt_all = (int*)p;                     p += (size_t)NTOT * sizeof(int);
    int* rp_all  = (int*)p;                     p += (size_t)NTOT * sizeof(int);
    int* cur_all = (int*)p;                     p += (size_t)NTOT * sizeof(int);
    int* ci_all  = (int*)p;                     p += (size_t)NP_TOT * sizeof(int);
    int* bsum    = (int*)p;                     p += 1024 * sizeof(int);
    p = align16(p);
    unsigned short* Wt0 = (unsigned short*)p;   p += (size_t)32768 * sizeof(unsigned short);
    unsigned short* Wt1 = (unsigned short*)p;   p += (size_t)32768 * sizeof(unsigned short);
    unsigned short* Wt2 = (unsigned short*)p;   p += (size_t)32768 * sizeof(unsigned short);
    unsigned short* Wt3 = (unsigned short*)p;   p += (size_t)32768 * sizeof(unsigned short);

    float* f0 = (float*)d_out;  // x_f fp32 master lives in d_out

    const int TB = 256;

    // ---- embeds ----
    embed_kernel<3, false, true><<<((size_t)NV * W + TB - 1) / TB, TB, 0, stream>>>(
        vertices, Wv, bv, nullptr, x_vb, NV);
    embed_kernel<12, false, true><<<((size_t)NE * W + TB - 1) / TB, TB, 0, stream>>>(
        edges, We, be, nullptr, x_eb, NE);
    embed_kernel<14, true, false><<<((size_t)NF * W + TB - 1) / TB, TB, 0, stream>>>(
        faces, Wf, bf_, f0, nullptr, NF);

    // ---- weight converts ----
    wconv4_kernel<<<512, TB, 0, stream>>>(Wv2e, We2f, Wm0, Wm1, Wt0, Wt1, Wt2, Wt3);

    // ---- CSR build ----
    (void)hipMemsetAsync(cnt_all, 0, (size_t)NTOT * sizeof(int), stream);
    hist3_kernel<<<(NP_TOT + TB - 1) / TB, TB, 0, stream>>>(etv_e, N_EV, fte_f, N_FE, ftf_dst,
                                                            N_FF, cnt_all, off1, off2);
    int nb = (NTOT + 1023) / 1024;
    scan_pass1<<<nb, TB, 0, stream>>>(cnt_all, NTOT, bsum);
    scan_pass2<<<1, 1024, 0, stream>>>(bsum, nb);
    scan_pass3<<<nb, TB, 0, stream>>>(cnt_all, NTOT, bsum, rp_all, cur_all);
    fill3_kernel<<<(NP_TOT + TB - 1) / TB, TB, 0, stream>>>(etv_e, etv_v, N_EV, fte_f, fte_e,
                                                            N_FE, ftf_dst, ftf_src, N_FF,
                                                            cur_all, off1, off2, ci_all);

    // ---- fused convs ----
    // conv1: V2E. xs=x_vb, xd=x_eb (bf16, in-place: blocks touch only own rows)
    fused_conv<true, false, true><<<(NE + ROWS - 1) / ROWS, TB, 0, stream>>>(
        x_vb, nullptr, x_eb, nullptr, x_eb, rp_all, ci_all, Wt0, bv2e, NE);
    // conv2: E2F. xs=x_eb, xd=f0 fp32 in-place; also emit bf16 copy f0b for conv3's gather
    fused_conv<false, true, true><<<(NF + ROWS - 1) / ROWS, TB, 0, stream>>>(
        x_eb, f0, nullptr, f0, f0b, rp_all + off1, ci_all, Wt1, be2f, NF);
    // conv3: F2F layer0. xs=f0b, xd=f0 -> f1 (+f1b for conv4's gather)
    fused_conv<false, true, true><<<(NF + ROWS - 1) / ROWS, TB, 0, stream>>>(
        f0b, f0, nullptr, f1, f1b, rp_all + off2, ci_all, Wt2, bm0, NF);
    // conv4: F2F layer1. xs=f1b, xd=f1 -> f0 (d_out, final)
    fused_conv<false, true, false><<<(NF + ROWS - 1) / ROWS, TB, 0, stream>>>(
        f1b, f1, nullptr, f0, nullptr, rp_all + off2, ci_all, Wt3, bm1, NF);
}

// Round 6
// 754.679 us; speedup vs baseline: 2.9618x; 1.3289x over previous
//
#include <hip/hip_runtime.h>

#define W 128
#define ROWS 32      // dst rows per block in fused_conv
#define HSTRIDE 264  // bf16 elems per h row (256 + 8 pad)
#define BSHIFT 10    // 1024 dst ids per bucket
#define BSZ 1024

typedef short bf16x8 __attribute__((ext_vector_type(8)));
typedef float f32x4 __attribute__((ext_vector_type(4)));

__device__ __forceinline__ float lrelu(float x) { return x > 0.f ? x : 0.01f * x; }

// RTNE float -> bf16 (as ushort bit pattern)
__device__ __forceinline__ unsigned short f2bf(float f) {
    unsigned u = __float_as_uint(f);
    u += 0x7fffu + ((u >> 16) & 1u);
    return (unsigned short)(u >> 16);
}
__device__ __forceinline__ float bfu(unsigned short u) {
    return __uint_as_float(((unsigned)u) << 16);
}
__device__ __forceinline__ float4 bf4_to_f4(ushort4 u) {
    return make_float4(bfu(u.x), bfu(u.y), bfu(u.z), bfu(u.w));
}
__device__ __forceinline__ ushort4 f4_to_bf4(float4 f) {
    return make_ushort4(f2bf(f.x), f2bf(f.y), f2bf(f.z), f2bf(f.w));
}
__device__ __forceinline__ float4 min4(float4 a, float4 b) {
    return make_float4(fminf(a.x, b.x), fminf(a.y, b.y), fminf(a.z, b.z), fminf(a.w, b.w));
}
__device__ __forceinline__ float4 lrelu4(float4 v) {
    return make_float4(lrelu(v.x), lrelu(v.y), lrelu(v.z), lrelu(v.w));
}

// ---- initial embed: lrelu(in @ Wm + b) -> bf16 ----
template <int K>
__global__ void embed_kernel(const float* __restrict__ in, const float* __restrict__ Wm,
                             const float* __restrict__ bias, unsigned short* __restrict__ outb,
                             int n) {
    int t = blockIdx.x * 256 + threadIdx.x;
    int row = t >> 7, c = t & 127;
    if (row >= n) return;
    float s = bias[c];
#pragma unroll
    for (int k = 0; k < K; k++) s += in[row * K + k] * Wm[k * W + c];
    outb[(size_t)row * W + c] = f2bf(lrelu(s));
}

// ---- fused weight convert: 4x [256][128] fp32 -> [128][256] bf16 transposed ----
__global__ void wconv4_kernel(const float* __restrict__ W0, const float* __restrict__ W1,
                              const float* __restrict__ W2, const float* __restrict__ W3,
                              unsigned short* __restrict__ T0, unsigned short* __restrict__ T1,
                              unsigned short* __restrict__ T2, unsigned short* __restrict__ T3) {
    int which = blockIdx.x >> 7;
    const float* Wm = (which == 0) ? W0 : (which == 1) ? W1 : (which == 2) ? W2 : W3;
    unsigned short* Wt = (which == 0) ? T0 : (which == 1) ? T1 : (which == 2) ? T2 : T3;
    int i = (blockIdx.x & 127) * 256 + threadIdx.x;  // 32768 per matrix
    int k = i >> 7, n = i & 127;
    Wt[n * 256 + k] = f2bf(Wm[k * W + n]);
}

// ---- bucket-partitioned CSR build over concatenated dst domain ----
// dst' mapping: job0 (etv): [0,NE)  job1 (fte): [NE,NE+NF)  job2 (ftf): [NE+NF,NE+2NF)
struct PairSrc {
    const int* d0; const int* s0; int n0;
    const int* d1; const int* s1; int n1;
    const int* d2; const int* s2; int n2;
    int NE, NF;
};

__device__ __forceinline__ void pair_at(const PairSrc& P, int g, int& dp, int& sp) {
    dp = -1; sp = 0;
    if (g < P.n0) { dp = P.d0[g]; sp = P.s0[g]; }
    else if (g < P.n0 + P.n1) { int j = g - P.n0; dp = P.NE + P.d1[j]; sp = P.s1[j]; }
    else if (g < P.n0 + P.n1 + P.n2) { int j = g - P.n0 - P.n1; dp = P.NE + P.NF + P.d2[j]; sp = P.s2[j]; }
}

#define CHUNK 4096  // pairs per block in partition passes (16 per thread)

__global__ __launch_bounds__(256) void part_hist(PairSrc P, int* __restrict__ gcnt) {
    __shared__ int hist[512];
    int t = threadIdx.x;
    for (int j = t; j < 512; j += 256) hist[j] = 0;
    __syncthreads();
    int g0 = blockIdx.x * CHUNK;
#pragma unroll
    for (int k = 0; k < 16; k++) {
        int dp, sp;
        pair_at(P, g0 + k * 256 + t, dp, sp);
        if (dp >= 0) atomicAdd(&hist[dp >> BSHIFT], 1);
    }
    __syncthreads();
    for (int j = t; j < 512; j += 256)
        if (hist[j]) atomicAdd(&gcnt[j], hist[j]);
}

__global__ void bucket_scan(const int* __restrict__ gcnt, int* __restrict__ goff,
                            int* __restrict__ gcur, int NB, int NP) {
    __shared__ int s[512];
    int t = threadIdx.x;
    int v = (t < NB) ? gcnt[t] : 0;
    s[t] = v;
    __syncthreads();
    for (int off = 1; off < 512; off <<= 1) {
        int add = (t >= off) ? s[t - off] : 0;
        __syncthreads();
        s[t] += add;
        __syncthreads();
    }
    if (t < NB) {
        int excl = s[t] - v;
        goff[t] = excl;
        gcur[t] = excl;
    }
    if (t == 0) goff[NB] = NP;
}

__global__ __launch_bounds__(256) void part_scatter(PairSrc P, int* __restrict__ gcur,
                                                    int2* __restrict__ pairs) {
    __shared__ int hist[512];
    __shared__ int base[512];
    int t = threadIdx.x;
    for (int j = t; j < 512; j += 256) hist[j] = 0;
    __syncthreads();
    int g0 = blockIdx.x * CHUNK;
    int dv[16], sv[16], rk[16];
#pragma unroll
    for (int k = 0; k < 16; k++) {
        pair_at(P, g0 + k * 256 + t, dv[k], sv[k]);
        rk[k] = (dv[k] >= 0) ? atomicAdd(&hist[dv[k] >> BSHIFT], 1) : 0;
    }
    __syncthreads();
    for (int j = t; j < 512; j += 256)
        base[j] = hist[j] ? atomicAdd(&gcur[j], hist[j]) : 0;
    __syncthreads();
#pragma unroll
    for (int k = 0; k < 16; k++) {
        if (dv[k] >= 0) pairs[base[dv[k] >> BSHIFT] + rk[k]] = make_int2(dv[k], sv[k]);
    }
}

// one block per bucket: LDS counting sort -> rowptr + ci (writes confined to bucket window)
__global__ __launch_bounds__(256) void bucket_sort(const int2* __restrict__ pairs,
                                                   const int* __restrict__ goff, int D, int NP,
                                                   int* __restrict__ rowptr,
                                                   int* __restrict__ ci) {
    __shared__ int hist[BSZ];
    __shared__ int base[BSZ];
    __shared__ int tsum[256];
    int b = blockIdx.x, t = threadIdx.x;
    int d0 = b << BSHIFT;
    int roff = goff[b], rend = goff[b + 1], cnt = rend - roff;
    for (int j = t; j < BSZ; j += 256) hist[j] = 0;
    __syncthreads();
    for (int i = t; i < cnt; i += 256) {
        int2 pr = pairs[roff + i];
        atomicAdd(&hist[pr.x - d0], 1);
    }
    __syncthreads();
    // exclusive scan hist -> base
    int loc[4], s0 = 0;
#pragma unroll
    for (int k = 0; k < 4; k++) {
        loc[k] = s0;
        s0 += hist[t * 4 + k];
    }
    tsum[t] = s0;
    __syncthreads();
    for (int off = 1; off < 256; off <<= 1) {
        int add = (t >= off) ? tsum[t - off] : 0;
        __syncthreads();
        tsum[t] += add;
        __syncthreads();
    }
    int ebase = tsum[t] - s0;
#pragma unroll
    for (int k = 0; k < 4; k++) base[t * 4 + k] = ebase + loc[k];
    __syncthreads();
    // rowptr (coalesced)
    for (int j = t; j < BSZ; j += 256) {
        int d = d0 + j;
        if (d < D) rowptr[d] = roff + base[j];
    }
    if (b == 0 && t == 0) rowptr[D] = NP;
    // cursors (reuse hist)
    for (int j = t; j < BSZ; j += 256) hist[j] = base[j];
    __syncthreads();
    for (int i = t; i < cnt; i += 256) {
        int2 pr = pairs[roff + i];
        int pos = roff + atomicAdd(&hist[pr.x - d0], 1);
        ci[pos] = pr.y;
    }
}

// ---- fused conv (bf16 tables): gather-min -> h -> MFMA -> residual ----
template <bool OUT_F32>
__global__ __launch_bounds__(256) void fused_conv_bf(
    const unsigned short* __restrict__ xsb, const unsigned short* __restrict__ xdb,
    unsigned short* __restrict__ out_b, float* __restrict__ out_f,
    const int* __restrict__ rowptr, const int* __restrict__ ci,
    const unsigned short* __restrict__ Wt, const float* __restrict__ bias, int n_dst) {
    __shared__ unsigned short h[ROWS][HSTRIDE];
    int wave = threadIdx.x >> 6, lane = threadIdx.x & 63;
    int li = lane & 31, half = lane >> 5;
    int r0 = blockIdx.x * ROWS;
    const ushort4* xs4 = (const ushort4*)xsb;

    int rbase = wave * 8 + half * 4;
    for (int rr = 0; rr < 4; rr++) {
        int r = rbase + rr;
        int d = r0 + r;
        float4 xdv = make_float4(0.f, 0.f, 0.f, 0.f);
        ushort4 xdu = make_ushort4(0, 0, 0, 0);
        float4 mn = make_float4(3.4e38f, 3.4e38f, 3.4e38f, 3.4e38f);
        int deg = 0;
        if (d < n_dst) {
            int beg = rowptr[d], end = rowptr[d + 1];
            deg = end - beg;
            xdu = ((const ushort4*)xdb)[(size_t)d * 32 + li];
            xdv = bf4_to_f4(xdu);
            int j = beg;
            while (j + 8 <= end) {
                int s0 = ci[j], s1 = ci[j + 1], s2 = ci[j + 2], s3 = ci[j + 3];
                int s4 = ci[j + 4], s5 = ci[j + 5], s6 = ci[j + 6], s7 = ci[j + 7];
                ushort4 v0 = xs4[(size_t)s0 * 32 + li];
                ushort4 v1 = xs4[(size_t)s1 * 32 + li];
                ushort4 v2 = xs4[(size_t)s2 * 32 + li];
                ushort4 v3 = xs4[(size_t)s3 * 32 + li];
                ushort4 v4 = xs4[(size_t)s4 * 32 + li];
                ushort4 v5 = xs4[(size_t)s5 * 32 + li];
                ushort4 v6 = xs4[(size_t)s6 * 32 + li];
                ushort4 v7 = xs4[(size_t)s7 * 32 + li];
                float4 m01 = min4(bf4_to_f4(v0), bf4_to_f4(v1));
                float4 m23 = min4(bf4_to_f4(v2), bf4_to_f4(v3));
                float4 m45 = min4(bf4_to_f4(v4), bf4_to_f4(v5));
                float4 m67 = min4(bf4_to_f4(v6), bf4_to_f4(v7));
                mn = min4(mn, min4(min4(m01, m23), min4(m45, m67)));
                j += 8;
            }
            while (j + 2 <= end) {
                int s0 = ci[j], s1 = ci[j + 1];
                mn = min4(mn, min4(bf4_to_f4(xs4[(size_t)s0 * 32 + li]),
                                   bf4_to_f4(xs4[(size_t)s1 * 32 + li])));
                j += 2;
            }
            if (j < end) mn = min4(mn, bf4_to_f4(xs4[(size_t)ci[j] * 32 + li]));
        }
        float4 mx;
        mx.x = deg ? (xdv.x - mn.x) : 0.f;
        mx.y = deg ? (xdv.y - mn.y) : 0.f;
        mx.z = deg ? (xdv.z - mn.z) : 0.f;
        mx.w = deg ? (xdv.w - mn.w) : 0.f;
        *(ushort4*)&h[r][li * 4] = xdu;
        *(ushort4*)&h[r][128 + li * 4] = f4_to_bf4(mx);
    }
    __syncthreads();

    // --- MFMA phase
    int rt = wave >> 1;
    int ctbase = (wave & 1) * 4;
    int m = lane & 15, q = lane >> 4;
    f32x4 acc[4];
#pragma unroll
    for (int ct = 0; ct < 4; ct++) acc[ct] = (f32x4){0.f, 0.f, 0.f, 0.f};
    for (int k0 = 0; k0 < 256; k0 += 32) {
        bf16x8 a = *(const bf16x8*)&h[rt * 16 + m][k0 + q * 8];
#pragma unroll
        for (int ct = 0; ct < 4; ct++) {
            int n = (ctbase + ct) * 16 + m;
            bf16x8 b = *(const bf16x8*)&Wt[n * 256 + k0 + q * 8];
            acc[ct] = __builtin_amdgcn_mfma_f32_16x16x32_bf16(a, b, acc[ct], 0, 0, 0);
        }
    }

    // --- epilogue: residual from LDS h (exact bf16 copy of xd)
#pragma unroll
    for (int ct = 0; ct < 4; ct++) {
        int col = (ctbase + ct) * 16 + m;
        float bc = bias[col];
#pragma unroll
        for (int reg = 0; reg < 4; reg++) {
            int r_l = rt * 16 + q * 4 + reg;
            int row = r0 + r_l;
            if (row < n_dst) {
                float xold = bfu(h[r_l][col]);
                float val = xold + lrelu(acc[ct][reg] + bc);
                if (OUT_F32) out_f[(size_t)row * W + col] = val;
                else out_b[(size_t)row * W + col] = f2bf(val);
            }
        }
    }
}

// ---- fused conv1 (V2E): on-the-fly vertex embed in gather (12B rows!) ----
__global__ __launch_bounds__(256) void fused_conv_v2e(
    const float* __restrict__ verts, const float* __restrict__ Wv, const float* __restrict__ bv,
    unsigned short* __restrict__ x_eb, const int* __restrict__ rowptr,
    const int* __restrict__ ci, const unsigned short* __restrict__ Wt,
    const float* __restrict__ bias, int n_dst) {
    __shared__ unsigned short h[ROWS][HSTRIDE];
    int wave = threadIdx.x >> 6, lane = threadIdx.x & 63;
    int li = lane & 31, half = lane >> 5;
    int r0 = blockIdx.x * ROWS;

    // per-lane embed weights for channels 4li..4li+3
    float4 wv0 = *(const float4*)&Wv[0 * W + 4 * li];
    float4 wv1 = *(const float4*)&Wv[1 * W + 4 * li];
    float4 wv2 = *(const float4*)&Wv[2 * W + 4 * li];
    float4 bvv = *(const float4*)&bv[4 * li];

    int rbase = wave * 8 + half * 4;
    for (int rr = 0; rr < 4; rr++) {
        int r = rbase + rr;
        int d = r0 + r;
        float4 xdv = make_float4(0.f, 0.f, 0.f, 0.f);
        ushort4 xdu = make_ushort4(0, 0, 0, 0);
        float4 mn = make_float4(3.4e38f, 3.4e38f, 3.4e38f, 3.4e38f);
        int deg = 0;
        if (d < n_dst) {
            int beg = rowptr[d], end = rowptr[d + 1];
            deg = end - beg;
            xdu = ((const ushort4*)x_eb)[(size_t)d * 32 + li];
            xdv = bf4_to_f4(xdu);
            for (int j = beg; j < end; j++) {
                int s = ci[j];
                float a0 = verts[3 * s], a1 = verts[3 * s + 1], a2 = verts[3 * s + 2];
                float4 e;
                e.x = bvv.x + a0 * wv0.x + a1 * wv1.x + a2 * wv2.x;
                e.y = bvv.y + a0 * wv0.y + a1 * wv1.y + a2 * wv2.y;
                e.z = bvv.z + a0 * wv0.z + a1 * wv1.z + a2 * wv2.z;
                e.w = bvv.w + a0 * wv0.w + a1 * wv1.w + a2 * wv2.w;
                mn = min4(mn, lrelu4(e));
            }
        }
        float4 mx;
        mx.x = deg ? (xdv.x - mn.x) : 0.f;
        mx.y = deg ? (xdv.y - mn.y) : 0.f;
        mx.z = deg ? (xdv.z - mn.z) : 0.f;
        mx.w = deg ? (xdv.w - mn.w) : 0.f;
        *(ushort4*)&h[r][li * 4] = xdu;
        *(ushort4*)&h[r][128 + li * 4] = f4_to_bf4(mx);
    }
    __syncthreads();

    int rt = wave >> 1;
    int ctbase = (wave & 1) * 4;
    int m = lane & 15, q = lane >> 4;
    f32x4 acc[4];
#pragma unroll
    for (int ct = 0; ct < 4; ct++) acc[ct] = (f32x4){0.f, 0.f, 0.f, 0.f};
    for (int k0 = 0; k0 < 256; k0 += 32) {
        bf16x8 a = *(const bf16x8*)&h[rt * 16 + m][k0 + q * 8];
#pragma unroll
        for (int ct = 0; ct < 4; ct++) {
            int n = (ctbase + ct) * 16 + m;
            bf16x8 b = *(const bf16x8*)&Wt[n * 256 + k0 + q * 8];
            acc[ct] = __builtin_amdgcn_mfma_f32_16x16x32_bf16(a, b, acc[ct], 0, 0, 0);
        }
    }
#pragma unroll
    for (int ct = 0; ct < 4; ct++) {
        int col = (ctbase + ct) * 16 + m;
        float bc = bias[col];
#pragma unroll
        for (int reg = 0; reg < 4; reg++) {
            int r_l = rt * 16 + q * 4 + reg;
            int row = r0 + r_l;
            if (row < n_dst) {
                float xold = bfu(h[r_l][col]);
                x_eb[(size_t)row * W + col] = f2bf(xold + lrelu(acc[ct][reg] + bc));
            }
        }
    }
}

static inline char* alignp(char* p, size_t a) {
    return (char*)(((uintptr_t)p + a - 1) & ~(uintptr_t)(a - 1));
}

extern "C" void kernel_launch(void* const* d_in, const int* in_sizes, int n_in,
                              void* d_out, int out_size, void* d_ws, size_t ws_size,
                              hipStream_t stream) {
    const float* vertices = (const float*)d_in[0];
    const float* edges    = (const float*)d_in[1];
    const float* faces    = (const float*)d_in[2];
    const int* etv_v   = (const int*)d_in[3];
    const int* etv_e   = (const int*)d_in[4];
    const int* fte_e   = (const int*)d_in[5];
    const int* fte_f   = (const int*)d_in[6];
    const int* ftf_src = (const int*)d_in[7];
    const int* ftf_dst = (const int*)d_in[8];
    const float* Wv   = (const float*)d_in[9];
    const float* bv   = (const float*)d_in[10];
    const float* We   = (const float*)d_in[11];
    const float* be   = (const float*)d_in[12];
    const float* Wf   = (const float*)d_in[13];
    const float* bf_  = (const float*)d_in[14];
    const float* Wv2e = (const float*)d_in[15];
    const float* bv2e = (const float*)d_in[16];
    const float* We2f = (const float*)d_in[17];
    const float* be2f = (const float*)d_in[18];
    const float* Wm0  = (const float*)d_in[19];
    const float* bm0  = (const float*)d_in[20];
    const float* Wm1  = (const float*)d_in[21];
    const float* bm1  = (const float*)d_in[22];

    const int NV = in_sizes[0] / 3;
    const int NE = in_sizes[1] / 12;
    const int NF = in_sizes[2] / 14;
    const int N_EV = in_sizes[3];
    const int N_FE = in_sizes[5];
    const int N_FF = in_sizes[7];
    (void)NV; (void)n_in; (void)out_size; (void)ws_size;

    const int D = NE + NF + NF;           // concatenated dst domain
    const int NP = N_EV + N_FE + N_FF;    // total pairs
    const int NB = (D + BSZ - 1) >> BSHIFT;

    // ---- ws layout ----
    char* p = (char*)d_ws;
    unsigned short* x_eb = (unsigned short*)p;  p += (size_t)NE * W * sizeof(unsigned short);
    unsigned short* f0b  = (unsigned short*)p;  p += (size_t)NF * W * sizeof(unsigned short);
    unsigned short* f1b  = (unsigned short*)p;  p += (size_t)NF * W * sizeof(unsigned short);
    p = alignp(p, 16);
    int2* pairs = (int2*)p;                     p += (size_t)NP * sizeof(int2);
    int* ci     = (int*)p;                      p += (size_t)NP * sizeof(int);
    int* rowptr = (int*)p;                      p += (size_t)(D + 1) * sizeof(int);
    int* gcnt   = (int*)p;                      p += 512 * sizeof(int);
    int* goff   = (int*)p;                      p += 513 * sizeof(int);
    int* gcur   = (int*)p;                      p += 512 * sizeof(int);
    p = alignp(p, 16);
    unsigned short* Wt0 = (unsigned short*)p;   p += (size_t)32768 * sizeof(unsigned short);
    unsigned short* Wt1 = (unsigned short*)p;   p += (size_t)32768 * sizeof(unsigned short);
    unsigned short* Wt2 = (unsigned short*)p;   p += (size_t)32768 * sizeof(unsigned short);
    unsigned short* Wt3 = (unsigned short*)p;   p += (size_t)32768 * sizeof(unsigned short);

    float* out_f = (float*)d_out;
    const int TB = 256;

    // ---- embeds (bf16); x_v folded into conv1 ----
    embed_kernel<12><<<((size_t)NE * W + TB - 1) / TB, TB, 0, stream>>>(edges, We, be, x_eb, NE);
    embed_kernel<14><<<((size_t)NF * W + TB - 1) / TB, TB, 0, stream>>>(faces, Wf, bf_, f0b, NF);
    wconv4_kernel<<<512, TB, 0, stream>>>(Wv2e, We2f, Wm0, Wm1, Wt0, Wt1, Wt2, Wt3);

    // ---- bucket-partitioned CSR build ----
    PairSrc P = {etv_e, etv_v, N_EV, fte_f, fte_e, N_FE, ftf_dst, ftf_src, N_FF, NE, NF};
    (void)hipMemsetAsync(gcnt, 0, 512 * sizeof(int), stream);
    int ablocks = (NP + CHUNK - 1) / CHUNK;
    part_hist<<<ablocks, TB, 0, stream>>>(P, gcnt);
    bucket_scan<<<1, 512, 0, stream>>>(gcnt, goff, gcur, NB, NP);
    part_scatter<<<ablocks, TB, 0, stream>>>(P, gcur, pairs);
    bucket_sort<<<NB, TB, 0, stream>>>(pairs, goff, D, NP, rowptr, ci);

    // ---- fused convs (all-bf16 chain) ----
    // conv1: V2E (vertex embed on the fly), x_eb in-place
    fused_conv_v2e<<<(NE + ROWS - 1) / ROWS, TB, 0, stream>>>(vertices, Wv, bv, x_eb, rowptr, ci,
                                                              Wt0, bv2e, NE);
    // conv2: E2F, gather x_eb, dst f0b in-place
    fused_conv_bf<false><<<(NF + ROWS - 1) / ROWS, TB, 0, stream>>>(
        x_eb, f0b, f0b, nullptr, rowptr + NE, ci, Wt1, be2f, NF);
    // conv3: F2F layer0, f0b -> f1b
    fused_conv_bf<false><<<(NF + ROWS - 1) / ROWS, TB, 0, stream>>>(
        f0b, f0b, f1b, nullptr, rowptr + NE + NF, ci, Wt2, bm0, NF);
    // conv4: F2F layer1, f1b -> d_out (fp32)
    fused_conv_bf<true><<<(NF + ROWS - 1) / ROWS, TB, 0, stream>>>(
        f1b, f1b, nullptr, out_f, rowptr + NE + NF, ci, Wt3, bm1, NF);
}

// Round 7
// 748.282 us; speedup vs baseline: 2.9872x; 1.0085x over previous
//
#include <hip/hip_runtime.h>

#define W 128
#define ROWS 32      // dst rows per block in fused_conv
#define BSHIFT 10    // 1024 dst ids per bucket
#define BSZ 1024

typedef short bf16x8 __attribute__((ext_vector_type(8)));
typedef float f32x4 __attribute__((ext_vector_type(4)));

__device__ __forceinline__ float lrelu(float x) { return x > 0.f ? x : 0.01f * x; }

// RTNE float -> bf16 (as ushort bit pattern)
__device__ __forceinline__ unsigned short f2bf(float f) {
    unsigned u = __float_as_uint(f);
    u += 0x7fffu + ((u >> 16) & 1u);
    return (unsigned short)(u >> 16);
}
__device__ __forceinline__ float bfu(unsigned short u) {
    return __uint_as_float(((unsigned)u) << 16);
}
__device__ __forceinline__ float4 bf4_to_f4(ushort4 u) {
    return make_float4(bfu(u.x), bfu(u.y), bfu(u.z), bfu(u.w));
}
__device__ __forceinline__ ushort4 f4_to_bf4(float4 f) {
    return make_ushort4(f2bf(f.x), f2bf(f.y), f2bf(f.z), f2bf(f.w));
}
// monotonic uint encoding of float (order-preserving): min(enc) == enc(min)
__device__ __forceinline__ unsigned enc_f(float f) {
    unsigned b = __float_as_uint(f);
    return (b & 0x80000000u) ? ~b : (b | 0x80000000u);
}
__device__ __forceinline__ float dec_f(unsigned e) {
    unsigned b = (e & 0x80000000u) ? (e ^ 0x80000000u) : ~e;
    return __uint_as_float(b);
}

// ---- initial embed: lrelu(in @ Wm + b) -> bf16 ----
template <int K>
__global__ void embed_kernel(const float* __restrict__ in, const float* __restrict__ Wm,
                             const float* __restrict__ bias, unsigned short* __restrict__ outb,
                             int n) {
    int t = blockIdx.x * 256 + threadIdx.x;
    int row = t >> 7, c = t & 127;
    if (row >= n) return;
    float s = bias[c];
#pragma unroll
    for (int k = 0; k < K; k++) s += in[row * K + k] * Wm[k * W + c];
    outb[(size_t)row * W + c] = f2bf(lrelu(s));
}

// ---- fused weight convert: 4x [256][128] fp32 -> [128][256] bf16 transposed ----
__global__ void wconv4_kernel(const float* __restrict__ W0, const float* __restrict__ W1,
                              const float* __restrict__ W2, const float* __restrict__ W3,
                              unsigned short* __restrict__ T0, unsigned short* __restrict__ T1,
                              unsigned short* __restrict__ T2, unsigned short* __restrict__ T3) {
    int which = blockIdx.x >> 7;
    const float* Wm = (which == 0) ? W0 : (which == 1) ? W1 : (which == 2) ? W2 : W3;
    unsigned short* Wt = (which == 0) ? T0 : (which == 1) ? T1 : (which == 2) ? T2 : T3;
    int i = (blockIdx.x & 127) * 256 + threadIdx.x;  // 32768 per matrix
    int k = i >> 7, n = i & 127;
    Wt[n * 256 + k] = f2bf(Wm[k * W + n]);
}

// ---- bucket-partitioned CSR build over concatenated dst domain ----
struct PairSrc {
    const int* d0; const int* s0; int n0;
    const int* d1; const int* s1; int n1;
    const int* d2; const int* s2; int n2;
    int NE, NF;
};

__device__ __forceinline__ void pair_at(const PairSrc& P, int g, int& dp, int& sp) {
    dp = -1; sp = 0;
    if (g < P.n0) { dp = P.d0[g]; sp = P.s0[g]; }
    else if (g < P.n0 + P.n1) { int j = g - P.n0; dp = P.NE + P.d1[j]; sp = P.s1[j]; }
    else if (g < P.n0 + P.n1 + P.n2) { int j = g - P.n0 - P.n1; dp = P.NE + P.NF + P.d2[j]; sp = P.s2[j]; }
}

#define CHUNK 4096

__global__ __launch_bounds__(256) void part_hist(PairSrc P, int* __restrict__ gcnt) {
    __shared__ int hist[512];
    int t = threadIdx.x;
    for (int j = t; j < 512; j += 256) hist[j] = 0;
    __syncthreads();
    int g0 = blockIdx.x * CHUNK;
#pragma unroll
    for (int k = 0; k < 16; k++) {
        int dp, sp;
        pair_at(P, g0 + k * 256 + t, dp, sp);
        if (dp >= 0) atomicAdd(&hist[dp >> BSHIFT], 1);
    }
    __syncthreads();
    for (int j = t; j < 512; j += 256)
        if (hist[j]) atomicAdd(&gcnt[j], hist[j]);
}

__global__ void bucket_scan(const int* __restrict__ gcnt, int* __restrict__ goff,
                            int* __restrict__ gcur, int NB, int NP) {
    __shared__ int s[512];
    int t = threadIdx.x;
    int v = (t < NB) ? gcnt[t] : 0;
    s[t] = v;
    __syncthreads();
    for (int off = 1; off < 512; off <<= 1) {
        int add = (t >= off) ? s[t - off] : 0;
        __syncthreads();
        s[t] += add;
        __syncthreads();
    }
    if (t < NB) {
        int excl = s[t] - v;
        goff[t] = excl;
        gcur[t] = excl;
    }
    if (t == 0) goff[NB] = NP;
}

__global__ __launch_bounds__(256) void part_scatter(PairSrc P, int* __restrict__ gcur,
                                                    int2* __restrict__ pairs) {
    __shared__ int hist[512];
    __shared__ int base[512];
    int t = threadIdx.x;
    for (int j = t; j < 512; j += 256) hist[j] = 0;
    __syncthreads();
    int g0 = blockIdx.x * CHUNK;
    int dv[16], sv[16], rk[16];
#pragma unroll
    for (int k = 0; k < 16; k++) {
        pair_at(P, g0 + k * 256 + t, dv[k], sv[k]);
        rk[k] = (dv[k] >= 0) ? atomicAdd(&hist[dv[k] >> BSHIFT], 1) : 0;
    }
    __syncthreads();
    for (int j = t; j < 512; j += 256)
        base[j] = hist[j] ? atomicAdd(&gcur[j], hist[j]) : 0;
    __syncthreads();
#pragma unroll
    for (int k = 0; k < 16; k++) {
        if (dv[k] >= 0) pairs[base[dv[k] >> BSHIFT] + rk[k]] = make_int2(dv[k], sv[k]);
    }
}

// one block per bucket: LDS counting sort -> rowptr + (ci, cd)
__global__ __launch_bounds__(256) void bucket_sort(const int2* __restrict__ pairs,
                                                   const int* __restrict__ goff, int D, int NP,
                                                   int* __restrict__ rowptr,
                                                   int* __restrict__ ci, int* __restrict__ cd) {
    __shared__ int hist[BSZ];
    __shared__ int base[BSZ];
    __shared__ int tsum[256];
    int b = blockIdx.x, t = threadIdx.x;
    int d0 = b << BSHIFT;
    int roff = goff[b], rend = goff[b + 1], cnt = rend - roff;
    for (int j = t; j < BSZ; j += 256) hist[j] = 0;
    __syncthreads();
    for (int i = t; i < cnt; i += 256) {
        int2 pr = pairs[roff + i];
        atomicAdd(&hist[pr.x - d0], 1);
    }
    __syncthreads();
    int loc[4], s0 = 0;
#pragma unroll
    for (int k = 0; k < 4; k++) {
        loc[k] = s0;
        s0 += hist[t * 4 + k];
    }
    tsum[t] = s0;
    __syncthreads();
    for (int off = 1; off < 256; off <<= 1) {
        int add = (t >= off) ? tsum[t - off] : 0;
        __syncthreads();
        tsum[t] += add;
        __syncthreads();
    }
    int ebase = tsum[t] - s0;
#pragma unroll
    for (int k = 0; k < 4; k++) base[t * 4 + k] = ebase + loc[k];
    __syncthreads();
    for (int j = t; j < BSZ; j += 256) {
        int d = d0 + j;
        if (d < D) rowptr[d] = roff + base[j];
    }
    if (b == 0 && t == 0) rowptr[D] = NP;
    for (int j = t; j < BSZ; j += 256) hist[j] = base[j];
    __syncthreads();
    for (int i = t; i < cnt; i += 256) {
        int2 pr = pairs[roff + i];
        int pos = roff + atomicAdd(&hist[pr.x - d0], 1);
        ci[pos] = pr.y;
        cd[pos] = pr.x;
    }
}

// =====================================================================
// fused conv, edge-parallel gather:
//   phase A: init LDS mins (enc-fp32) ; load own xd rows + degrees
//   phase B: stream pairs (independent loads) -> 4x LDS atomicMin each
//   phase C: mins -> mx ; rewrite LDS as bf16 h tile (union, same 16.9KB)
//   phase D: MFMA MLP + residual epilogue
// =====================================================================
#define SMW 132  // dwords per LDS row (128 + 4 pad); 132*4B == 264 shorts

template <bool OUT_F32>
__global__ __launch_bounds__(256) void fused_conv_ep(
    const unsigned short* __restrict__ xsb, const unsigned short* __restrict__ xdb,
    unsigned short* __restrict__ out_b, float* __restrict__ out_f,
    const int* __restrict__ rowptr, const int* __restrict__ ci, const int* __restrict__ cd,
    int off_conv, const unsigned short* __restrict__ Wt, const float* __restrict__ bias,
    int n_dst) {
    __shared__ unsigned smem[ROWS * SMW];  // union: enc-fp32 mins, then bf16 h
    int t = threadIdx.x;
    int wave = t >> 6, lane = t & 63;
    int li = lane & 31, halfIdx = t >> 5;  // 0..7
    int r0 = blockIdx.x * ROWS;

    for (int j = t; j < ROWS * SMW; j += 256) smem[j] = 0xFFFFFFFFu;

    int rbase = halfIdx * 4;
    ushort4 xdu[4];
    int degv[4];
#pragma unroll
    for (int rr = 0; rr < 4; rr++) {
        int d = r0 + rbase + rr;
        xdu[rr] = make_ushort4(0, 0, 0, 0);
        degv[rr] = 0;
        if (d < n_dst) {
            xdu[rr] = ((const ushort4*)xdb)[(size_t)d * 32 + li];
            degv[rr] = rowptr[d + 1] - rowptr[d];
        }
    }
    __syncthreads();

    // --- phase B: edge-parallel gather-min
    int rEnd = (r0 + ROWS < n_dst) ? r0 + ROWS : n_dst;
    int prBeg = rowptr[r0], prEnd = rowptr[rEnd];
    const ushort4* xs4 = (const ushort4*)xsb;
    int dbase = off_conv + r0;
    int p = prBeg + halfIdx;
    while (p + 24 < prEnd) {  // 4 independent pair-iterations in flight
        int p0 = p, p1 = p + 8, p2 = p + 16, p3 = p + 24;
        int s0 = ci[p0], s1 = ci[p1], s2 = ci[p2], s3 = ci[p3];
        int d0 = cd[p0] - dbase, d1 = cd[p1] - dbase, d2 = cd[p2] - dbase, d3 = cd[p3] - dbase;
        float4 f0 = bf4_to_f4(xs4[(size_t)s0 * 32 + li]);
        float4 f1 = bf4_to_f4(xs4[(size_t)s1 * 32 + li]);
        float4 f2 = bf4_to_f4(xs4[(size_t)s2 * 32 + li]);
        float4 f3 = bf4_to_f4(xs4[(size_t)s3 * 32 + li]);
        unsigned* m0 = &smem[d0 * SMW + 4 * li];
        unsigned* m1 = &smem[d1 * SMW + 4 * li];
        unsigned* m2 = &smem[d2 * SMW + 4 * li];
        unsigned* m3 = &smem[d3 * SMW + 4 * li];
        atomicMin(&m0[0], enc_f(f0.x)); atomicMin(&m0[1], enc_f(f0.y));
        atomicMin(&m0[2], enc_f(f0.z)); atomicMin(&m0[3], enc_f(f0.w));
        atomicMin(&m1[0], enc_f(f1.x)); atomicMin(&m1[1], enc_f(f1.y));
        atomicMin(&m1[2], enc_f(f1.z)); atomicMin(&m1[3], enc_f(f1.w));
        atomicMin(&m2[0], enc_f(f2.x)); atomicMin(&m2[1], enc_f(f2.y));
        atomicMin(&m2[2], enc_f(f2.z)); atomicMin(&m2[3], enc_f(f2.w));
        atomicMin(&m3[0], enc_f(f3.x)); atomicMin(&m3[1], enc_f(f3.y));
        atomicMin(&m3[2], enc_f(f3.z)); atomicMin(&m3[3], enc_f(f3.w));
        p += 32;
    }
    while (p < prEnd) {
        int s = ci[p];
        int dl = cd[p] - dbase;
        float4 f = bf4_to_f4(xs4[(size_t)s * 32 + li]);
        unsigned* m = &smem[dl * SMW + 4 * li];
        atomicMin(&m[0], enc_f(f.x)); atomicMin(&m[1], enc_f(f.y));
        atomicMin(&m[2], enc_f(f.z)); atomicMin(&m[3], enc_f(f.w));
        p += 8;
    }
    __syncthreads();

    // --- phase C: mins -> mx, then rewrite smem as h
    float4 mxv[4];
#pragma unroll
    for (int rr = 0; rr < 4; rr++) {
        int r = rbase + rr;
        uint4 mu = *(const uint4*)&smem[r * SMW + 4 * li];
        float4 xdv = bf4_to_f4(xdu[rr]);
        mxv[rr].x = degv[rr] ? (xdv.x - dec_f(mu.x)) : 0.f;
        mxv[rr].y = degv[rr] ? (xdv.y - dec_f(mu.y)) : 0.f;
        mxv[rr].z = degv[rr] ? (xdv.z - dec_f(mu.z)) : 0.f;
        mxv[rr].w = degv[rr] ? (xdv.w - dec_f(mu.w)) : 0.f;
    }
    __syncthreads();
    unsigned short* h = (unsigned short*)smem;  // stride 264 shorts per row
#pragma unroll
    for (int rr = 0; rr < 4; rr++) {
        int r = rbase + rr;
        *(ushort4*)&h[r * 264 + 4 * li] = xdu[rr];
        *(ushort4*)&h[r * 264 + 128 + 4 * li] = f4_to_bf4(mxv[rr]);
    }
    __syncthreads();

    // --- phase D: MFMA
    int rt = wave >> 1;
    int ctbase = (wave & 1) * 4;
    int m = lane & 15, q = lane >> 4;
    f32x4 acc[4];
#pragma unroll
    for (int ct = 0; ct < 4; ct++) acc[ct] = (f32x4){0.f, 0.f, 0.f, 0.f};
    for (int k0 = 0; k0 < 256; k0 += 32) {
        bf16x8 a = *(const bf16x8*)&h[(rt * 16 + m) * 264 + k0 + q * 8];
#pragma unroll
        for (int ct = 0; ct < 4; ct++) {
            int n = (ctbase + ct) * 16 + m;
            bf16x8 b = *(const bf16x8*)&Wt[n * 256 + k0 + q * 8];
            acc[ct] = __builtin_amdgcn_mfma_f32_16x16x32_bf16(a, b, acc[ct], 0, 0, 0);
        }
    }
#pragma unroll
    for (int ct = 0; ct < 4; ct++) {
        int col = (ctbase + ct) * 16 + m;
        float bc = bias[col];
#pragma unroll
        for (int reg = 0; reg < 4; reg++) {
            int r_l = rt * 16 + q * 4 + reg;
            int row = r0 + r_l;
            if (row < n_dst) {
                float xold = bfu(h[r_l * 264 + col]);
                float val = xold + lrelu(acc[ct][reg] + bc);
                if (OUT_F32) out_f[(size_t)row * W + col] = val;
                else out_b[(size_t)row * W + col] = f2bf(val);
            }
        }
    }
}

// ---- v2e variant: src row = on-the-fly vertex embed (12 B loads) ----
__global__ __launch_bounds__(256) void fused_conv_v2e_ep(
    const float* __restrict__ verts, const float* __restrict__ Wv, const float* __restrict__ bv,
    unsigned short* __restrict__ x_eb, const int* __restrict__ rowptr,
    const int* __restrict__ ci, const int* __restrict__ cd,
    const unsigned short* __restrict__ Wt, const float* __restrict__ bias, int n_dst) {
    __shared__ unsigned smem[ROWS * SMW];
    int t = threadIdx.x;
    int wave = t >> 6, lane = t & 63;
    int li = lane & 31, halfIdx = t >> 5;
    int r0 = blockIdx.x * ROWS;

    for (int j = t; j < ROWS * SMW; j += 256) smem[j] = 0xFFFFFFFFu;

    float4 wv0 = *(const float4*)&Wv[0 * W + 4 * li];
    float4 wv1 = *(const float4*)&Wv[1 * W + 4 * li];
    float4 wv2 = *(const float4*)&Wv[2 * W + 4 * li];
    float4 bvv = *(const float4*)&bv[4 * li];

    int rbase = halfIdx * 4;
    ushort4 xdu[4];
    int degv[4];
#pragma unroll
    for (int rr = 0; rr < 4; rr++) {
        int d = r0 + rbase + rr;
        xdu[rr] = make_ushort4(0, 0, 0, 0);
        degv[rr] = 0;
        if (d < n_dst) {
            xdu[rr] = ((const ushort4*)x_eb)[(size_t)d * 32 + li];
            degv[rr] = rowptr[d + 1] - rowptr[d];
        }
    }
    __syncthreads();

    int rEnd = (r0 + ROWS < n_dst) ? r0 + ROWS : n_dst;
    int prBeg = rowptr[r0], prEnd = rowptr[rEnd];
    int dbase = r0;  // conv1 offset is 0
    for (int p = prBeg + halfIdx; p < prEnd; p += 8) {
        int s = ci[p];
        int dl = cd[p] - dbase;
        float a0 = verts[3 * s], a1 = verts[3 * s + 1], a2 = verts[3 * s + 2];
        float4 e;
        e.x = lrelu(bvv.x + a0 * wv0.x + a1 * wv1.x + a2 * wv2.x);
        e.y = lrelu(bvv.y + a0 * wv0.y + a1 * wv1.y + a2 * wv2.y);
        e.z = lrelu(bvv.z + a0 * wv0.z + a1 * wv1.z + a2 * wv2.z);
        e.w = lrelu(bvv.w + a0 * wv0.w + a1 * wv1.w + a2 * wv2.w);
        unsigned* m = &smem[dl * SMW + 4 * li];
        atomicMin(&m[0], enc_f(e.x)); atomicMin(&m[1], enc_f(e.y));
        atomicMin(&m[2], enc_f(e.z)); atomicMin(&m[3], enc_f(e.w));
    }
    __syncthreads();

    float4 mxv[4];
#pragma unroll
    for (int rr = 0; rr < 4; rr++) {
        int r = rbase + rr;
        uint4 mu = *(const uint4*)&smem[r * SMW + 4 * li];
        float4 xdv = bf4_to_f4(xdu[rr]);
        mxv[rr].x = degv[rr] ? (xdv.x - dec_f(mu.x)) : 0.f;
        mxv[rr].y = degv[rr] ? (xdv.y - dec_f(mu.y)) : 0.f;
        mxv[rr].z = degv[rr] ? (xdv.z - dec_f(mu.z)) : 0.f;
        mxv[rr].w = degv[rr] ? (xdv.w - dec_f(mu.w)) : 0.f;
    }
    __syncthreads();
    unsigned short* h = (unsigned short*)smem;
#pragma unroll
    for (int rr = 0; rr < 4; rr++) {
        int r = rbase + rr;
        *(ushort4*)&h[r * 264 + 4 * li] = xdu[rr];
        *(ushort4*)&h[r * 264 + 128 + 4 * li] = f4_to_bf4(mxv[rr]);
    }
    __syncthreads();

    int rt = wave >> 1;
    int ctbase = (wave & 1) * 4;
    int m = lane & 15, q = lane >> 4;
    f32x4 acc[4];
#pragma unroll
    for (int ct = 0; ct < 4; ct++) acc[ct] = (f32x4){0.f, 0.f, 0.f, 0.f};
    for (int k0 = 0; k0 < 256; k0 += 32) {
        bf16x8 a = *(const bf16x8*)&h[(rt * 16 + m) * 264 + k0 + q * 8];
#pragma unroll
        for (int ct = 0; ct < 4; ct++) {
            int n = (ctbase + ct) * 16 + m;
            bf16x8 b = *(const bf16x8*)&Wt[n * 256 + k0 + q * 8];
            acc[ct] = __builtin_amdgcn_mfma_f32_16x16x32_bf16(a, b, acc[ct], 0, 0, 0);
        }
    }
#pragma unroll
    for (int ct = 0; ct < 4; ct++) {
        int col = (ctbase + ct) * 16 + m;
        float bc = bias[col];
#pragma unroll
        for (int reg = 0; reg < 4; reg++) {
            int r_l = rt * 16 + q * 4 + reg;
            int row = r0 + r_l;
            if (row < n_dst) {
                float xold = bfu(h[r_l * 264 + col]);
                x_eb[(size_t)row * W + col] = f2bf(xold + lrelu(acc[ct][reg] + bc));
            }
        }
    }
}

static inline char* alignp(char* p, size_t a) {
    return (char*)(((uintptr_t)p + a - 1) & ~(uintptr_t)(a - 1));
}

extern "C" void kernel_launch(void* const* d_in, const int* in_sizes, int n_in,
                              void* d_out, int out_size, void* d_ws, size_t ws_size,
                              hipStream_t stream) {
    const float* vertices = (const float*)d_in[0];
    const float* edges    = (const float*)d_in[1];
    const float* faces    = (const float*)d_in[2];
    const int* etv_v   = (const int*)d_in[3];
    const int* etv_e   = (const int*)d_in[4];
    const int* fte_e   = (const int*)d_in[5];
    const int* fte_f   = (const int*)d_in[6];
    const int* ftf_src = (const int*)d_in[7];
    const int* ftf_dst = (const int*)d_in[8];
    const float* Wv   = (const float*)d_in[9];
    const float* bv   = (const float*)d_in[10];
    const float* We   = (const float*)d_in[11];
    const float* be   = (const float*)d_in[12];
    const float* Wf   = (const float*)d_in[13];
    const float* bf_  = (const float*)d_in[14];
    const float* Wv2e = (const float*)d_in[15];
    const float* bv2e = (const float*)d_in[16];
    const float* We2f = (const float*)d_in[17];
    const float* be2f = (const float*)d_in[18];
    const float* Wm0  = (const float*)d_in[19];
    const float* bm0  = (const float*)d_in[20];
    const float* Wm1  = (const float*)d_in[21];
    const float* bm1  = (const float*)d_in[22];

    const int NV = in_sizes[0] / 3;
    const int NE = in_sizes[1] / 12;
    const int NF = in_sizes[2] / 14;
    const int N_EV = in_sizes[3];
    const int N_FE = in_sizes[5];
    const int N_FF = in_sizes[7];
    (void)NV; (void)n_in; (void)out_size; (void)ws_size;

    const int D = NE + NF + NF;
    const int NP = N_EV + N_FE + N_FF;
    const int NB = (D + BSZ - 1) >> BSHIFT;

    // ---- ws layout ----
    char* p = (char*)d_ws;
    unsigned short* x_eb = (unsigned short*)p;  p += (size_t)NE * W * sizeof(unsigned short);
    unsigned short* f0b  = (unsigned short*)p;  p += (size_t)NF * W * sizeof(unsigned short);
    unsigned short* f1b  = (unsigned short*)p;  p += (size_t)NF * W * sizeof(unsigned short);
    p = alignp(p, 16);
    int2* pairs = (int2*)p;                     p += (size_t)NP * sizeof(int2);
    int* ci     = (int*)p;                      p += (size_t)NP * sizeof(int);
    int* cd     = (int*)p;                      p += (size_t)NP * sizeof(int);
    int* rowptr = (int*)p;                      p += (size_t)(D + 1) * sizeof(int);
    int* gcnt   = (int*)p;                      p += 512 * sizeof(int);
    int* goff   = (int*)p;                      p += 513 * sizeof(int);
    int* gcur   = (int*)p;                      p += 512 * sizeof(int);
    p = alignp(p, 16);
    unsigned short* Wt0 = (unsigned short*)p;   p += (size_t)32768 * sizeof(unsigned short);
    unsigned short* Wt1 = (unsigned short*)p;   p += (size_t)32768 * sizeof(unsigned short);
    unsigned short* Wt2 = (unsigned short*)p;   p += (size_t)32768 * sizeof(unsigned short);
    unsigned short* Wt3 = (unsigned short*)p;   p += (size_t)32768 * sizeof(unsigned short);

    float* out_f = (float*)d_out;
    const int TB = 256;

    // ---- embeds (bf16); x_v folded into conv1 ----
    embed_kernel<12><<<((size_t)NE * W + TB - 1) / TB, TB, 0, stream>>>(edges, We, be, x_eb, NE);
    embed_kernel<14><<<((size_t)NF * W + TB - 1) / TB, TB, 0, stream>>>(faces, Wf, bf_, f0b, NF);
    wconv4_kernel<<<512, TB, 0, stream>>>(Wv2e, We2f, Wm0, Wm1, Wt0, Wt1, Wt2, Wt3);

    // ---- bucket-partitioned CSR build ----
    PairSrc P = {etv_e, etv_v, N_EV, fte_f, fte_e, N_FE, ftf_dst, ftf_src, N_FF, NE, NF};
    (void)hipMemsetAsync(gcnt, 0, 512 * sizeof(int), stream);
    int ablocks = (NP + CHUNK - 1) / CHUNK;
    part_hist<<<ablocks, TB, 0, stream>>>(P, gcnt);
    bucket_scan<<<1, 512, 0, stream>>>(gcnt, goff, gcur, NB, NP);
    part_scatter<<<ablocks, TB, 0, stream>>>(P, gcur, pairs);
    bucket_sort<<<NB, TB, 0, stream>>>(pairs, goff, D, NP, rowptr, ci, cd);

    // ---- fused convs (edge-parallel gather) ----
    fused_conv_v2e_ep<<<(NE + ROWS - 1) / ROWS, TB, 0, stream>>>(vertices, Wv, bv, x_eb, rowptr,
                                                                 ci, cd, Wt0, bv2e, NE);
    fused_conv_ep<false><<<(NF + ROWS - 1) / ROWS, TB, 0, stream>>>(
        x_eb, f0b, f0b, nullptr, rowptr + NE, ci, cd, NE, Wt1, be2f, NF);
    fused_conv_ep<false><<<(NF + ROWS - 1) / ROWS, TB, 0, stream>>>(
        f0b, f0b, f1b, nullptr, rowptr + NE + NF, ci, cd, NE + NF, Wt2, bm0, NF);
    fused_conv_ep<true><<<(NF + ROWS - 1) / ROWS, TB, 0, stream>>>(
        f1b, f1b, nullptr, out_f, rowptr + NE + NF, ci, cd, NE + NF, Wt3, bm1, NF);
}